// Round 5
// baseline (243.480 us; speedup 1.0000x reference)
//
#include <hip/hip_runtime.h>
#include <stdint.h>

#define N_NODES 50000
#define N_EDGES 800000
#define DIM     128
#define NB   196                 // dst buckets: dst>>8
#define CAP  8192                // fixed slots per bucket in 'packed'
#define CHUNK 2048               // edges per scatter block
#define NBLK 391                 // ceil(800000/2048)
#define GCAP 4096                // LDS edge cap for gather blocks (mean 1024 @64 nodes)
#define G3NODES 128              // nodes per gather3 block (2 lanes/node)
#define G3CAP 4096               // LDS edge cap for gather3 blocks (mean 2048)
#define ZBLK 98                  // h3s zero blocks: 25000 f32x4 / 256
#define SLICES 8                 // Hb feature slices (16 feats = 32B each)
#define GCHUNKS 782              // ceil(50000/64) node chunks for gather

typedef __attribute__((ext_vector_type(8))) unsigned short ushort8_t;
typedef __attribute__((ext_vector_type(8))) short bfrag;    // 8 bf16 = 4 VGPR
typedef __attribute__((ext_vector_type(4))) float f32x4;

// ---------------- Threefry-2x32 (exact JAX 20-round) ----------------
__host__ __device__ inline void threefry2x32(uint32_t k0, uint32_t k1,
                                             uint32_t x0, uint32_t x1,
                                             uint32_t& o0, uint32_t& o1) {
    uint32_t ks0 = k0, ks1 = k1, ks2 = k0 ^ k1 ^ 0x1BD11BDAu;
    uint32_t v0 = x0 + ks0, v1 = x1 + ks1;
#define TF_R(r) { v0 += v1; v1 = (v1 << (r)) | (v1 >> (32 - (r))); v1 ^= v0; }
    TF_R(13) TF_R(15) TF_R(26) TF_R(6)
    v0 += ks1; v1 += ks2 + 1u;
    TF_R(17) TF_R(29) TF_R(16) TF_R(24)
    v0 += ks2; v1 += ks0 + 2u;
    TF_R(13) TF_R(15) TF_R(26) TF_R(6)
    v0 += ks0; v1 += ks1 + 3u;
    TF_R(17) TF_R(29) TF_R(16) TF_R(24)
    v0 += ks1; v1 += ks2 + 4u;
    TF_R(13) TF_R(15) TF_R(26) TF_R(6)
    v0 += ks2; v1 += ks0 + 5u;
#undef TF_R
    o0 = v0; o1 = v1;
}

__device__ inline float drop_scale(uint32_t kk0, uint32_t kk1, uint32_t i) {
    uint32_t b0, b1;
    threefry2x32(kk0, kk1, 0u, i, b0, b1);
    uint32_t bits = b0 ^ b1;               // partitionable 32-bit path (verified R0)
    return (bits >> 31) ? 0.0f : 2.0f;     // keep iff u < 0.5 iff top bit 0
}

__device__ inline float bf2f(ushort u) {
    return __uint_as_float(((uint32_t)u) << 16);
}
__device__ inline float bfpair_lo(uint32_t u) { return __uint_as_float(u << 16); }
__device__ inline float bfpair_hi(uint32_t u) { return __uint_as_float(u & 0xffff0000u); }

__device__ inline ushort f2bf_rne(float f) {
    uint32_t bits = __float_as_uint(f);
    uint32_t lsb = (bits >> 16) & 1u;
    bits += 0x7fffu + lsb;                 // round-to-nearest-even
    return (ushort)(bits >> 16);
}

// 8-feat accumulate from a uint4 of bf16 pairs, scaled by d
__device__ inline void acc8(float* acc, uint4 u, float d) {
    acc[0] += d * bfpair_lo(u.x); acc[1] += d * bfpair_hi(u.x);
    acc[2] += d * bfpair_lo(u.y); acc[3] += d * bfpair_hi(u.y);
    acc[4] += d * bfpair_lo(u.z); acc[5] += d * bfpair_hi(u.z);
    acc[6] += d * bfpair_lo(u.w); acc[7] += d * bfpair_hi(u.w);
}
__device__ inline void acc8p(float* acc, uint4 u) {
    acc[0] += bfpair_lo(u.x); acc[1] += bfpair_hi(u.x);
    acc[2] += bfpair_lo(u.y); acc[3] += bfpair_hi(u.y);
    acc[4] += bfpair_lo(u.z); acc[5] += bfpair_hi(u.z);
    acc[6] += bfpair_lo(u.w); acc[7] += bfpair_hi(u.w);
}

// ---------------- MFMA GEMM body: H = A @ W, bf16 out, Hb[slice][v][16] -----
// 8 slices of 16 feats (32B/node): slice = 1.6MB -> resident in one XCD L2
// even alongside col16/Bb streams (gather uses slice = blockIdx&7 = XCD id).
// F32A=1: A read from fp32, converted in registers (layer 1)
// SCALE=1: pre-multiply rows by dis[row] (layer 2); SCALE=0: raw (layer 1)
template<int F32A, int SCALE>
__device__ inline void gemm_body(const ushort* __restrict__ Xb,
                                 const float* __restrict__ Xf,
                                 const ushort* __restrict__ Wt,
                                 const float* __restrict__ dis,
                                 ushort* __restrict__ Hb, int gb, int tid) {
    int w = tid >> 6, lane = tid & 63;
    int m0 = gb * 128 + w * 32;
    int lrow = lane & 15, quad = lane >> 4;
    f32x4 acc[2][8] = {};
    for (int kt = 0; kt < DIM; kt += 32) {
        bfrag a[2], b[8];
        #pragma unroll
        for (int t = 0; t < 2; ++t) {
            int m = m0 + t * 16 + lrow;
            if (m >= N_NODES) m = 0;
            if (F32A) {
                const float* p = Xf + (size_t)m * DIM + kt + quad * 8;
                f32x4 v0 = *(const f32x4*)p;
                f32x4 v1 = *(const f32x4*)(p + 4);
                #pragma unroll
                for (int j = 0; j < 4; ++j) {
                    a[t][j]     = (short)f2bf_rne(v0[j]);
                    a[t][j + 4] = (short)f2bf_rne(v1[j]);
                }
            } else {
                a[t] = *(const bfrag*)(Xb + (size_t)m * DIM + kt + quad * 8);
            }
        }
        #pragma unroll
        for (int c = 0; c < 8; ++c) {
            int n = c * 16 + lrow;
            b[c] = *(const bfrag*)(Wt + (size_t)n * DIM + kt + quad * 8);
        }
        #pragma unroll
        for (int t = 0; t < 2; ++t)
            #pragma unroll
            for (int c = 0; c < 8; ++c)
                acc[t][c] = __builtin_amdgcn_mfma_f32_16x16x32_bf16(a[t], b[c], acc[t][c], 0, 0, 0);
    }
    #pragma unroll
    for (int t = 0; t < 2; ++t) {
        #pragma unroll
        for (int r = 0; r < 4; ++r) {
            int rowi = m0 + t * 16 + quad * 4 + r;
            if (rowi < N_NODES) {
                float dv = SCALE ? dis[rowi] : 1.0f;
                #pragma unroll
                for (int c = 0; c < 8; ++c) {
                    // feat = c*16 + lrow  -> slice = c, off = lrow
                    float z = SCALE ? acc[t][c][r] * dv : acc[t][c][r];
                    Hb[((size_t)c * N_NODES + rowi) * 16 + lrow] = f2bf_rne(z);
                }
            }
        }
    }
}

// ---- k_prep: scatter FIRST (R18: latency-bound blocks at t=0), then W
// transposes, then h3s zeroing (folds away a memset dispatch).
__global__ __launch_bounds__(256) void k_prep(const float* __restrict__ W1,
                                              const float* __restrict__ W2,
                                              ushort* __restrict__ W1t,
                                              ushort* __restrict__ W2t,
                                              const int* __restrict__ src,
                                              const int* __restrict__ dst,
                                              uint32_t* __restrict__ gcur,
                                              uint32_t* __restrict__ packed,
                                              float* __restrict__ h3s) {
    __shared__ uint32_t h[NB];
    int b = blockIdx.x;
    int t = threadIdx.x;
    if (b < NBLK) {
        uint32_t dc[CHUNK / 256], sc[CHUNK / 256];   // static-indexed reg cache
        if (t < NB) h[t] = 0u;
        __syncthreads();
        int base = b * CHUNK;
        #pragma unroll
        for (int i = 0; i < CHUNK / 256; ++i) {
            int e = base + i * 256 + t;
            if (e < N_EDGES) {
                dc[i] = (uint32_t)dst[e];
                sc[i] = (uint32_t)src[e];
                atomicAdd(&h[dc[i] >> 8], 1u);
            } else {
                dc[i] = 0xffffffffu;
            }
        }
        __syncthreads();
        if (t < NB) {
            uint32_t c = h[t];
            h[t] = c ? atomicAdd(&gcur[t], c) : 0u;   // reserve contiguous run
        }
        __syncthreads();
        #pragma unroll
        for (int i = 0; i < CHUNK / 256; ++i) {
            if (dc[i] != 0xffffffffu) {
                uint32_t d = dc[i];
                uint32_t s = sc[i];
                uint32_t bk = d >> 8;
                uint32_t pos = atomicAdd(&h[bk], 1u);
                if (pos < CAP)
                    packed[(size_t)bk * CAP + pos] = ((d & 255u) << 16) | s;
            }
        }
    } else if (b < NBLK + 128) {
        int j = (b - NBLK) * 256 + t;              // 0..32767
        const float* W = (j < DIM * DIM) ? W1 : W2;
        ushort* Wt = (j < DIM * DIM) ? W1t : W2t;
        int i = j & (DIM * DIM - 1);
        int k = i >> 7, n = i & 127;
        Wt[n * DIM + k] = f2bf_rne(W[k * DIM + n]);
    } else {
        int idx = (b - NBLK - 128) * 256 + t;      // zero h3s (25000 f32x4)
        if (idx < (N_NODES * 2) / 4) {
            f32x4 z = {0.f, 0.f, 0.f, 0.f};
            ((f32x4*)h3s)[idx] = z;
        }
    }
}

// ---- k_fill: csr blocks (0..195, latency-bound, start at t=0) build the
// compact CSR + dis; gemm blocks (196..586) run layer-1 GEMM concurrently
// (reads only x/W1t — no dependence on csr output; writes UNSCALED Hb).
__global__ __launch_bounds__(256) void k_fill(const uint32_t* __restrict__ gcur,
                                              const uint32_t* __restrict__ packed,
                                              uint32_t* __restrict__ row,
                                              float* __restrict__ dis,
                                              ushort* __restrict__ col16,
                                              const float* __restrict__ x,
                                              const ushort* __restrict__ W1t,
                                              ushort* __restrict__ Hb) {
    __shared__ uint32_t sdeg[256];
    __shared__ uint32_t scan[256];
    __shared__ uint32_t cur[256];
    int b = blockIdx.x;
    int t = threadIdx.x;
    if (b >= NB) {                                  // layer-1 GEMM flavor
        gemm_body<1, 0>(nullptr, x, W1t, nullptr, Hb, b - NB, t);
        return;
    }
    uint32_t n = gcur[b];
    scan[t] = (t < b) ? gcur[t] : 0u;              // b <= 195 < 256
    __syncthreads();
    for (int off = 1; off < 256; off <<= 1) {
        uint32_t xx = (t >= off) ? scan[t - off] : 0u;
        __syncthreads();
        scan[t] += xx;
        __syncthreads();
    }
    uint32_t cbase = scan[255];
    __syncthreads();
    uint32_t pbase = (uint32_t)b * CAP;
    sdeg[t] = 0u;
    __syncthreads();
    for (uint32_t i = t; i < n; i += 256) {
        uint32_t u = packed[pbase + i];
        atomicAdd(&sdeg[u >> 16], 1u);
    }
    __syncthreads();
    uint32_t myd = sdeg[t];
    scan[t] = myd;
    __syncthreads();
    for (int off = 1; off < 256; off <<= 1) {
        uint32_t xx = (t >= off) ? scan[t - off] : 0u;
        __syncthreads();
        scan[t] += xx;
        __syncthreads();
    }
    uint32_t excl = scan[t] - myd;
    cur[t] = excl;
    int v = b * 256 + t;
    if (v <= N_NODES) row[v] = cbase + excl;       // compact; row[50000]=800000
    if (v < N_NODES)  dis[v] = 1.0f / sqrtf((float)(myd + 1u));
    __syncthreads();
    for (uint32_t i = t; i < n; i += 256) {        // re-read: L1-hot, no scratch
        uint32_t u = packed[pbase + i];
        uint32_t pos = cbase + atomicAdd(&cur[u >> 16], 1u);
        col16[pos] = (ushort)(u & 0xffffu);
    }
}

// ---------------- fused gather + bias + leaky + dropout [+ classifier] -------
// Block: slice sl = blockIdx&7 (16 feats, 1.6MB -> one XCD's L2), 64 nodes.
// Thread = (nl = tid>>2, q = (tid>>1)&1 -> 8-feat half, par = tid&1 -> edge
// parity). Parity halves the divergent serial edge chain; shfl_xor(1) merges.
// SRCDIS=1 (layer 1): Hb unscaled -> apply dis[s] per edge, dis[v] on self/out.
// CLS=1 (layer 2): fold 128->2 classifier; partial dot over this slice,
// 4-lane shfl reduce, one atomic pair per (node, slice).
template<int CLS, int SRCDIS>
__global__ __launch_bounds__(256) void k_gather_t(const uint32_t* __restrict__ row,
                                                  const ushort* __restrict__ col16,
                                                  const float* __restrict__ dis,
                                                  const ushort* __restrict__ Hb,
                                                  const float* __restrict__ bias,
                                                  ushort* __restrict__ OUTb,
                                                  const float* __restrict__ W3,
                                                  float* __restrict__ h3s,
                                                  uint32_t kk0, uint32_t kk1) {
    __shared__ ushort scol[GCAP];
    __shared__ uint32_t srow[65];
    int sl = blockIdx.x & 7;
    int c  = blockIdx.x >> 3;
    int tid = threadIdx.x;
    int nbase = c * 64;
    int nend = nbase + 64; if (nend > N_NODES) nend = N_NODES;
    int nloc = nend - nbase;
    for (int i = tid; i <= nloc; i += 256) srow[i] = row[nbase + i];
    __syncthreads();
    uint32_t eLo = srow[0];
    uint32_t count = srow[nloc] - eLo;
    bool staged = count <= GCAP;
    if (staged) {
        for (uint32_t i = tid; i < count; i += 256) scol[i] = col16[eLo + i];
    }
    __syncthreads();

    int nl  = tid >> 2;                // node in block (0..63)
    int q   = (tid >> 1) & 1;          // 8-feat half of the 16-feat slice
    int par = tid & 1;                 // edge-parity lane
    int v = nbase + nl;
    if (v >= N_NODES) return;
    float dv = dis[v];
    const ushort* Hf = Hb + (size_t)sl * N_NODES * 16;
    float acc[8];
    #pragma unroll
    for (int j = 0; j < 8; ++j) acc[j] = 0.f;
    if (par == 0) {                    // self-loop term once per (node,q)
        uint4 u = *(const uint4*)(Hf + (size_t)v * 16 + q * 8);
        acc8(acc, u, SRCDIS ? dv : 1.0f);
    }

    uint32_t e1 = srow[nl + 1] - eLo;
    uint32_t e = (srow[nl] - eLo) + (uint32_t)par;
    if (staged) {
        for (; e + 6 < e1; e += 8) {   // 4 edges per parity lane in flight
            uint32_t s0 = scol[e], s1 = scol[e + 2], s2 = scol[e + 4], s3 = scol[e + 6];
            uint4 u0 = *(const uint4*)(Hf + (size_t)s0 * 16 + q * 8);
            uint4 u1 = *(const uint4*)(Hf + (size_t)s1 * 16 + q * 8);
            uint4 u2 = *(const uint4*)(Hf + (size_t)s2 * 16 + q * 8);
            uint4 u3 = *(const uint4*)(Hf + (size_t)s3 * 16 + q * 8);
            if (SRCDIS) {
                float d0 = dis[s0], d1 = dis[s1], d2 = dis[s2], d3 = dis[s3];
                acc8(acc, u0, d0); acc8(acc, u1, d1);
                acc8(acc, u2, d2); acc8(acc, u3, d3);
            } else {
                acc8p(acc, u0); acc8p(acc, u1); acc8p(acc, u2); acc8p(acc, u3);
            }
        }
        for (; e < e1; e += 2) {
            uint32_t s0 = scol[e];
            uint4 u0 = *(const uint4*)(Hf + (size_t)s0 * 16 + q * 8);
            if (SRCDIS) acc8(acc, u0, dis[s0]);
            else        acc8p(acc, u0);
        }
    } else {
        for (; e < e1; e += 2) {
            uint32_t s0 = col16[eLo + e];
            uint4 u0 = *(const uint4*)(Hf + (size_t)s0 * 16 + q * 8);
            if (SRCDIS) acc8(acc, u0, dis[s0]);
            else        acc8p(acc, u0);
        }
    }

    // merge the two parity lanes (adjacent lanes, DPP xor-1)
    #pragma unroll
    for (int j = 0; j < 8; ++j) acc[j] += __shfl_xor(acc[j], 1);

    int jb = par * 4;                           // this lane finishes 4 feats
    int cb = sl * 16 + q * 8 + jb;
    uint32_t ib = (uint32_t)(v * DIM + cb);
    if (CLS == 0) {
        ushort4 o;
        float z0 = acc[jb + 0] * dv + bias[cb + 0];
        float z1 = acc[jb + 1] * dv + bias[cb + 1];
        float z2 = acc[jb + 2] * dv + bias[cb + 2];
        float z3 = acc[jb + 3] * dv + bias[cb + 3];
        z0 = (z0 >= 0.f) ? z0 : 0.01f * z0;  z0 *= drop_scale(kk0, kk1, ib + 0);
        z1 = (z1 >= 0.f) ? z1 : 0.01f * z1;  z1 *= drop_scale(kk0, kk1, ib + 1);
        z2 = (z2 >= 0.f) ? z2 : 0.01f * z2;  z2 *= drop_scale(kk0, kk1, ib + 2);
        z3 = (z3 >= 0.f) ? z3 : 0.01f * z3;  z3 *= drop_scale(kk0, kk1, ib + 3);
        o.x = f2bf_rne(z0); o.y = f2bf_rne(z1);
        o.z = f2bf_rne(z2); o.w = f2bf_rne(z3);
        *((ushort4*)(OUTb + (size_t)v * DIM + cb)) = o;   // 2 lanes -> 16B line
    } else {
        float o0 = 0.f, o1 = 0.f;
        #pragma unroll
        for (int jj = 0; jj < 4; ++jj) {
            float z = acc[jb + jj] * dv + bias[cb + jj];
            z = (z >= 0.f) ? z : 0.01f * z;
            z *= drop_scale(kk0, kk1, ib + jj);
            o0 += z * W3[(cb + jj) * 2 + 0];
            o1 += z * W3[(cb + jj) * 2 + 1];
        }
        // reduce the 4 lanes of this node (adjacent) -> slice partial
        o0 += __shfl_xor(o0, 1); o0 += __shfl_xor(o0, 2);
        o1 += __shfl_xor(o1, 1); o1 += __shfl_xor(o1, 2);
        if ((tid & 3) == 0) {
            atomicAdd(&h3s[v * 2 + 0], o0 * dv);   // src-side dis for layer 3
            atomicAdd(&h3s[v * 2 + 1], o1 * dv);
        }
    }
}

// ---------------- layer-2 MFMA GEMM launcher (dis-prescaled output) ----------
__global__ __launch_bounds__(256) void k_gemm_bf16(const ushort* __restrict__ Xb,
                                                   const ushort* __restrict__ Wt,
                                                   const float* __restrict__ dis,
                                                   ushort* __restrict__ Hb) {
    gemm_body<0, 1>(Xb, nullptr, Wt, dis, Hb, blockIdx.x, threadIdx.x);
}

// ---------------- fused layer-3 gather + bias + log_softmax, LDS-staged ------
// 2 lanes/node (alternate edges) halves the divergent serial loop; shfl_xor(1)
// combines the two partials.
__global__ __launch_bounds__(256) void k_gather3(const uint32_t* __restrict__ row,
                                                 const ushort* __restrict__ col16,
                                                 const float* __restrict__ dis,
                                                 const float* __restrict__ H3s,
                                                 const float* __restrict__ b3,
                                                 float* __restrict__ out) {
    __shared__ ushort scol[G3CAP];
    __shared__ uint32_t srow[G3NODES + 1];
    int tid = threadIdx.x;
    int nbase = blockIdx.x * G3NODES;
    int nend = nbase + G3NODES; if (nend > N_NODES) nend = N_NODES;
    int nloc = nend - nbase;
    for (int i = tid; i <= nloc; i += 256) srow[i] = row[nbase + i];
    __syncthreads();
    uint32_t eLo = srow[0];
    uint32_t count = srow[nloc] - eLo;
    bool staged = count <= G3CAP;
    if (staged) {
        for (uint32_t i = tid; i < count; i += 256) scol[i] = col16[eLo + i];
    }
    __syncthreads();

    int nl = tid >> 1;                 // node in block
    int par = tid & 1;                 // edge-parity lane
    int v = nbase + nl;
    if (v >= N_NODES) return;
    const float2* H2 = (const float2*)H3s;
    float z0 = 0.f, z1 = 0.f;
    if (par == 0) {                    // self term once
        float2 h = H2[v];
        z0 = h.x; z1 = h.y;
    }
    uint32_t e0 = srow[nl] - eLo, e1 = srow[nl + 1] - eLo;
    if (staged) {
        for (uint32_t e = e0 + par; e < e1; e += 2) {
            float2 ha = H2[scol[e]];
            z0 += ha.x; z1 += ha.y;
        }
    } else {
        for (uint32_t e = e0 + par; e < e1; e += 2) {
            float2 ha = H2[col16[eLo + e]];
            z0 += ha.x; z1 += ha.y;
        }
    }
    z0 += __shfl_xor(z0, 1);
    z1 += __shfl_xor(z1, 1);
    if (par) return;
    float dv = dis[v];
    z0 = z0 * dv + b3[0];
    z1 = z1 * dv + b3[1];
    float m = fmaxf(z0, z1);
    float lse = m + logf(expf(z0 - m) + expf(z1 - m));
    out[v * 2 + 0] = z0 - lse;
    out[v * 2 + 1] = z1 - lse;
}

extern "C" void kernel_launch(void* const* d_in, const int* in_sizes, int n_in,
                              void* d_out, int out_size, void* d_ws, size_t ws_size,
                              hipStream_t stream) {
    const float* x  = (const float*)d_in[0];
    const int*   ei = (const int*)d_in[1];
    const float* W1 = (const float*)d_in[2];
    const float* b1 = (const float*)d_in[3];
    const float* W2 = (const float*)d_in[4];
    const float* b2 = (const float*)d_in[5];
    const float* W3 = (const float*)d_in[6];
    const float* b3 = (const float*)d_in[7];
    float* out = (float*)d_out;

    const int* src = ei;
    const int* dst = ei + N_EDGES;

    // workspace layout (u32 units) -- all regions disjoint (R10 lesson)
    uint32_t* wsu = (uint32_t*)d_ws;
    float*    wsf = (float*)d_ws;
    uint32_t* gcur   = wsu;                       // [0, 196) -> pad 256
    uint32_t* row    = wsu + 256;                 // [256, 50257) -> pad 50304
    float*    dis    = wsf + 50304;               // [50304, 100304) -> pad 100352
    uint32_t* packed = wsu + 100352;              // 196*8192 -> [100352, 1705984)
    ushort*   col16  = (ushort*)(wsu + 1705984);  // 800000 u16 -> pad to 2106112
    ushort*   Hb     = (ushort*)(wsu + 2106112);  // [2106112, 5306112)
    ushort*   Bb     = (ushort*)(wsu + 8506112);  // [8506112, 11706112)
    ushort*   W1t    = (ushort*)(wsu + 11706112); // [11706112, 11714304)
    ushort*   W2t    = (ushort*)(wsu + 11714304); // [11714304, 11722496)
    float*    h3s    = wsf + 11722496;            // [11722496, 11822496)

    // dropout keys: threefry-partitionable fold-like split of key(42) (verified R0)
    uint32_t k1a, k1b, k2a, k2b;
    threefry2x32(0u, 42u, 0u, 0u, k1a, k1b);
    threefry2x32(0u, 42u, 0u, 1u, k2a, k2b);

    hipMemsetAsync(gcur, 0, 256 * sizeof(uint32_t), stream);

    // ---- A: scatter (first!) | W transpose | h3s zero ----
    k_prep<<<NBLK + 128 + ZBLK, 256, 0, stream>>>(W1, W2, W1t, W2t,
                                                  src, dst, gcur, packed, h3s);

    // ---- CSR fill (csr blocks) OVERLAPPED with layer-1 GEMM (gemm blocks) ----
    k_fill<<<NB + 391, 256, 0, stream>>>(gcur, packed, row, dis, col16,
                                         x, W1t, Hb);

    int ggrid = GCHUNKS * SLICES;                 // (64-node chunk, slice)

    // ---- layer 1 gather (applies dis[s] per edge since Hb is unscaled) ----
    k_gather_t<0, 1><<<ggrid, 256, 0, stream>>>(row, col16, dis, Hb, b1, Bb,
                                                nullptr, nullptr, k1a, k1b);

    // ---- layer 2 GEMM (dis-prescaled) + gather with fused classifier ----
    k_gemm_bf16<<<(N_NODES + 127) / 128, 256, 0, stream>>>(Bb, W2t, dis, Hb);
    k_gather_t<1, 0><<<ggrid, 256, 0, stream>>>(row, col16, dis, Hb, b2, nullptr,
                                                W3, h3s, k2a, k2b);

    // ---- layer 3 aggregate + log_softmax ----
    k_gather3<<<(N_NODES + G3NODES - 1) / G3NODES, 256, 0, stream>>>(row, col16, dis,
                                                                     h3s, b3, out);
}

// Round 6
// 213.857 us; speedup vs baseline: 1.1385x; 1.1385x over previous
//
#include <hip/hip_runtime.h>
#include <stdint.h>

#define N_NODES 50000
#define N_EDGES 800000
#define DIM     128
#define NB   196                 // dst buckets: dst>>8
#define CAP  8192                // fixed slots per bucket in 'packed'
#define CHUNK 2048               // edges per scatter block
#define NBLK 391                 // ceil(800000/2048)
#define GNODES 16                // nodes per gather block (50000 = 16*3125)
#define GGRID 3125
#define GCAP 2048                // LDS edge cap per gather block (mean 256)
#define G3NODES 128              // nodes per gather3 block (2 lanes/node)
#define G3CAP 4096               // LDS edge cap for gather3 blocks (mean 2048)
#define ZBLK 98                  // h3s zero blocks: 25000 f32x4 / 256

typedef __attribute__((ext_vector_type(8))) unsigned short ushort8_t;
typedef __attribute__((ext_vector_type(8))) short bfrag;    // 8 bf16 = 4 VGPR
typedef __attribute__((ext_vector_type(4))) float f32x4;

// ---------------- Threefry-2x32 (exact JAX 20-round) ----------------
__host__ __device__ inline void threefry2x32(uint32_t k0, uint32_t k1,
                                             uint32_t x0, uint32_t x1,
                                             uint32_t& o0, uint32_t& o1) {
    uint32_t ks0 = k0, ks1 = k1, ks2 = k0 ^ k1 ^ 0x1BD11BDAu;
    uint32_t v0 = x0 + ks0, v1 = x1 + ks1;
#define TF_R(r) { v0 += v1; v1 = (v1 << (r)) | (v1 >> (32 - (r))); v1 ^= v0; }
    TF_R(13) TF_R(15) TF_R(26) TF_R(6)
    v0 += ks1; v1 += ks2 + 1u;
    TF_R(17) TF_R(29) TF_R(16) TF_R(24)
    v0 += ks2; v1 += ks0 + 2u;
    TF_R(13) TF_R(15) TF_R(26) TF_R(6)
    v0 += ks0; v1 += ks1 + 3u;
    TF_R(17) TF_R(29) TF_R(16) TF_R(24)
    v0 += ks1; v1 += ks2 + 4u;
    TF_R(13) TF_R(15) TF_R(26) TF_R(6)
    v0 += ks2; v1 += ks0 + 5u;
#undef TF_R
    o0 = v0; o1 = v1;
}

__device__ inline float drop_scale(uint32_t kk0, uint32_t kk1, uint32_t i) {
    uint32_t b0, b1;
    threefry2x32(kk0, kk1, 0u, i, b0, b1);
    uint32_t bits = b0 ^ b1;               // partitionable 32-bit path (verified R0)
    return (bits >> 31) ? 0.0f : 2.0f;     // keep iff u < 0.5 iff top bit 0
}

__device__ inline float bf2f(ushort u) {
    return __uint_as_float(((uint32_t)u) << 16);
}
__device__ inline float bfpair_lo(uint32_t u) { return __uint_as_float(u << 16); }
__device__ inline float bfpair_hi(uint32_t u) { return __uint_as_float(u & 0xffff0000u); }

__device__ inline ushort f2bf_rne(float f) {
    uint32_t bits = __float_as_uint(f);
    uint32_t lsb = (bits >> 16) & 1u;
    bits += 0x7fffu + lsb;                 // round-to-nearest-even
    return (ushort)(bits >> 16);
}

// 8-feat accumulate from a uint4 of bf16 pairs (dword-wise unpack: 1 VALU/elem)
__device__ inline void acc8(float* acc, uint4 u, float d) {
    acc[0] += d * bfpair_lo(u.x); acc[1] += d * bfpair_hi(u.x);
    acc[2] += d * bfpair_lo(u.y); acc[3] += d * bfpair_hi(u.y);
    acc[4] += d * bfpair_lo(u.z); acc[5] += d * bfpair_hi(u.z);
    acc[6] += d * bfpair_lo(u.w); acc[7] += d * bfpair_hi(u.w);
}
__device__ inline void acc8p(float* acc, uint4 u) {
    acc[0] += bfpair_lo(u.x); acc[1] += bfpair_hi(u.x);
    acc[2] += bfpair_lo(u.y); acc[3] += bfpair_hi(u.y);
    acc[4] += bfpair_lo(u.z); acc[5] += bfpair_hi(u.z);
    acc[6] += bfpair_lo(u.w); acc[7] += bfpair_hi(u.w);
}

// ---------------- MFMA GEMM body: H = A @ W, bf16 out, Hb[v][128] -----------
// [v][128] layout: per edge the 16 gather lanes read one contiguous 256B row
// (measured best in R2: MLP + coalescing beat XCD L2-slicing, R3/R5 A/B).
// F32A=1: A read from fp32, converted in registers (layer 1)
// SCALE=1: pre-multiply rows by dis[row] (layer 2); SCALE=0: raw (layer 1)
template<int F32A, int SCALE>
__device__ inline void gemm_body(const ushort* __restrict__ Xb,
                                 const float* __restrict__ Xf,
                                 const ushort* __restrict__ Wt,
                                 const float* __restrict__ dis,
                                 ushort* __restrict__ Hb, int gb, int tid) {
    int w = tid >> 6, lane = tid & 63;
    int m0 = gb * 128 + w * 32;
    int lrow = lane & 15, quad = lane >> 4;
    f32x4 acc[2][8] = {};
    for (int kt = 0; kt < DIM; kt += 32) {
        bfrag a[2], b[8];
        #pragma unroll
        for (int t = 0; t < 2; ++t) {
            int m = m0 + t * 16 + lrow;
            if (m >= N_NODES) m = 0;
            if (F32A) {
                const float* p = Xf + (size_t)m * DIM + kt + quad * 8;
                f32x4 v0 = *(const f32x4*)p;
                f32x4 v1 = *(const f32x4*)(p + 4);
                #pragma unroll
                for (int j = 0; j < 4; ++j) {
                    a[t][j]     = (short)f2bf_rne(v0[j]);
                    a[t][j + 4] = (short)f2bf_rne(v1[j]);
                }
            } else {
                a[t] = *(const bfrag*)(Xb + (size_t)m * DIM + kt + quad * 8);
            }
        }
        #pragma unroll
        for (int c = 0; c < 8; ++c) {
            int n = c * 16 + lrow;
            b[c] = *(const bfrag*)(Wt + (size_t)n * DIM + kt + quad * 8);
        }
        #pragma unroll
        for (int t = 0; t < 2; ++t)
            #pragma unroll
            for (int c = 0; c < 8; ++c)
                acc[t][c] = __builtin_amdgcn_mfma_f32_16x16x32_bf16(a[t], b[c], acc[t][c], 0, 0, 0);
    }
    #pragma unroll
    for (int t = 0; t < 2; ++t) {
        #pragma unroll
        for (int r = 0; r < 4; ++r) {
            int rowi = m0 + t * 16 + quad * 4 + r;
            if (rowi < N_NODES) {
                float dv = SCALE ? dis[rowi] : 1.0f;
                #pragma unroll
                for (int c = 0; c < 8; ++c) {
                    int feat = c * 16 + lrow;
                    float z = SCALE ? acc[t][c][r] * dv : acc[t][c][r];
                    Hb[(size_t)rowi * DIM + feat] = f2bf_rne(z);
                }
            }
        }
    }
}

// ---- k_prep: scatter FIRST (R18: latency-bound blocks at t=0), then W
// transposes, then h3s zeroing (folds away a memset dispatch).
__global__ __launch_bounds__(256) void k_prep(const float* __restrict__ W1,
                                              const float* __restrict__ W2,
                                              ushort* __restrict__ W1t,
                                              ushort* __restrict__ W2t,
                                              const int* __restrict__ src,
                                              const int* __restrict__ dst,
                                              uint32_t* __restrict__ gcur,
                                              uint32_t* __restrict__ packed,
                                              float* __restrict__ h3s) {
    __shared__ uint32_t h[NB];
    int b = blockIdx.x;
    int t = threadIdx.x;
    if (b < NBLK) {
        uint32_t dc[CHUNK / 256], sc[CHUNK / 256];   // static-indexed reg cache
        if (t < NB) h[t] = 0u;
        __syncthreads();
        int base = b * CHUNK;
        #pragma unroll
        for (int i = 0; i < CHUNK / 256; ++i) {
            int e = base + i * 256 + t;
            if (e < N_EDGES) {
                dc[i] = (uint32_t)dst[e];
                sc[i] = (uint32_t)src[e];
                atomicAdd(&h[dc[i] >> 8], 1u);
            } else {
                dc[i] = 0xffffffffu;
            }
        }
        __syncthreads();
        if (t < NB) {
            uint32_t c = h[t];
            h[t] = c ? atomicAdd(&gcur[t], c) : 0u;   // reserve contiguous run
        }
        __syncthreads();
        #pragma unroll
        for (int i = 0; i < CHUNK / 256; ++i) {
            if (dc[i] != 0xffffffffu) {
                uint32_t d = dc[i];
                uint32_t s = sc[i];
                uint32_t bk = d >> 8;
                uint32_t pos = atomicAdd(&h[bk], 1u);
                if (pos < CAP)
                    packed[(size_t)bk * CAP + pos] = ((d & 255u) << 16) | s;
            }
        }
    } else if (b < NBLK + 128) {
        int j = (b - NBLK) * 256 + t;              // 0..32767
        const float* W = (j < DIM * DIM) ? W1 : W2;
        ushort* Wt = (j < DIM * DIM) ? W1t : W2t;
        int i = j & (DIM * DIM - 1);
        int k = i >> 7, n = i & 127;
        Wt[n * DIM + k] = f2bf_rne(W[k * DIM + n]);
    } else {
        int idx = (b - NBLK - 128) * 256 + t;      // zero h3s (25000 f32x4)
        if (idx < (N_NODES * 2) / 4) {
            f32x4 z = {0.f, 0.f, 0.f, 0.f};
            ((f32x4*)h3s)[idx] = z;
        }
    }
}

// ---- k_fill: csr blocks (0..195, latency-bound, start at t=0) build the
// compact CSR + dis; gemm blocks (196..586) run layer-1 GEMM concurrently
// (reads only x/W1t — no dependence on csr output; writes UNSCALED Hb).
__global__ __launch_bounds__(256) void k_fill(const uint32_t* __restrict__ gcur,
                                              const uint32_t* __restrict__ packed,
                                              uint32_t* __restrict__ row,
                                              float* __restrict__ dis,
                                              ushort* __restrict__ col16,
                                              const float* __restrict__ x,
                                              const ushort* __restrict__ W1t,
                                              ushort* __restrict__ Hb) {
    __shared__ uint32_t sdeg[256];
    __shared__ uint32_t scan[256];
    __shared__ uint32_t cur[256];
    int b = blockIdx.x;
    int t = threadIdx.x;
    if (b >= NB) {                                  // layer-1 GEMM flavor
        gemm_body<1, 0>(nullptr, x, W1t, nullptr, Hb, b - NB, t);
        return;
    }
    uint32_t n = gcur[b];
    scan[t] = (t < b) ? gcur[t] : 0u;              // b <= 195 < 256
    __syncthreads();
    for (int off = 1; off < 256; off <<= 1) {
        uint32_t xx = (t >= off) ? scan[t - off] : 0u;
        __syncthreads();
        scan[t] += xx;
        __syncthreads();
    }
    uint32_t cbase = scan[255];
    __syncthreads();
    uint32_t pbase = (uint32_t)b * CAP;
    sdeg[t] = 0u;
    __syncthreads();
    for (uint32_t i = t; i < n; i += 256) {
        uint32_t u = packed[pbase + i];
        atomicAdd(&sdeg[u >> 16], 1u);
    }
    __syncthreads();
    uint32_t myd = sdeg[t];
    scan[t] = myd;
    __syncthreads();
    for (int off = 1; off < 256; off <<= 1) {
        uint32_t xx = (t >= off) ? scan[t - off] : 0u;
        __syncthreads();
        scan[t] += xx;
        __syncthreads();
    }
    uint32_t excl = scan[t] - myd;
    cur[t] = excl;
    int v = b * 256 + t;
    if (v <= N_NODES) row[v] = cbase + excl;       // compact; row[50000]=800000
    if (v < N_NODES)  dis[v] = 1.0f / sqrtf((float)(myd + 1u));
    __syncthreads();
    for (uint32_t i = t; i < n; i += 256) {        // re-read: L1-hot, no scratch
        uint32_t u = packed[pbase + i];
        uint32_t pos = cbase + atomicAdd(&cur[u >> 16], 1u);
        col16[pos] = (ushort)(u & 0xffffu);
    }
}

// ---------------- fused gather + bias + leaky + dropout [+ classifier] -------
// R2-measured-best structure: block = 16 nodes, thread = (nl = tid>>4,
// q = tid&15 -> 8-feat slice). Wave = 4 nodes (max-of-4 divergence); per edge
// the node's 16 lanes read one contiguous 256B Hb row. R6: 8/4/1 unroll
// cascade doubles loads-in-flight on the latency-bound chain (R5 lesson: MLP
// per lane, not L2 slicing, is what this loop needs).
// SRCDIS=1 (layer 1): Hb unscaled -> apply dis[s] per edge, dis[v] on self/out.
// CLS=1 (layer 2): fold 128->2 classifier; 16-lane shfl reduce, one atomic
// pair per node.
template<int CLS, int SRCDIS>
__global__ __launch_bounds__(256) void k_gather_t(const uint32_t* __restrict__ row,
                                                  const ushort* __restrict__ col16,
                                                  const float* __restrict__ dis,
                                                  const ushort* __restrict__ Hb,
                                                  const float* __restrict__ bias,
                                                  ushort* __restrict__ OUTb,
                                                  const float* __restrict__ W3,
                                                  float* __restrict__ h3s,
                                                  uint32_t kk0, uint32_t kk1) {
    __shared__ ushort scol[GCAP];
    __shared__ uint32_t srow[GNODES + 1];
    int tid = threadIdx.x;
    int nbase = blockIdx.x * GNODES;
    if (tid <= GNODES) srow[tid] = row[nbase + tid];
    __syncthreads();
    uint32_t eLo = srow[0];
    uint32_t count = srow[GNODES] - eLo;
    bool staged = count <= GCAP;
    if (staged) {
        for (uint32_t i = tid; i < count; i += 256) scol[i] = col16[eLo + i];
    }
    __syncthreads();

    int nl = tid >> 4;                 // node in block (0..15)
    int q  = tid & 15;                 // 8-feat slice (0..15)
    int v = nbase + nl;                // always < N_NODES (50000 = 16*3125)
    float dv = dis[v];
    float acc[8];
    {
        uint4 u = *(const uint4*)(Hb + (size_t)v * DIM + q * 8);
        acc[0] = bfpair_lo(u.x); acc[1] = bfpair_hi(u.x);
        acc[2] = bfpair_lo(u.y); acc[3] = bfpair_hi(u.y);
        acc[4] = bfpair_lo(u.z); acc[5] = bfpair_hi(u.z);
        acc[6] = bfpair_lo(u.w); acc[7] = bfpair_hi(u.w);
        if (SRCDIS) {
            #pragma unroll
            for (int j = 0; j < 8; ++j) acc[j] *= dv;   // self-loop scale
        }
    }

    uint32_t e0 = srow[nl] - eLo, e1 = srow[nl + 1] - eLo;
    uint32_t e = e0;
    if (staged) {
        for (; e + 8 <= e1; e += 8) {      // 8 rows in flight (MLP)
            uint32_t s0 = scol[e],     s1 = scol[e + 1];
            uint32_t s2 = scol[e + 2], s3 = scol[e + 3];
            uint32_t s4 = scol[e + 4], s5 = scol[e + 5];
            uint32_t s6 = scol[e + 6], s7 = scol[e + 7];
            uint4 u0 = *(const uint4*)(Hb + (size_t)s0 * DIM + q * 8);
            uint4 u1 = *(const uint4*)(Hb + (size_t)s1 * DIM + q * 8);
            uint4 u2 = *(const uint4*)(Hb + (size_t)s2 * DIM + q * 8);
            uint4 u3 = *(const uint4*)(Hb + (size_t)s3 * DIM + q * 8);
            uint4 u4 = *(const uint4*)(Hb + (size_t)s4 * DIM + q * 8);
            uint4 u5 = *(const uint4*)(Hb + (size_t)s5 * DIM + q * 8);
            uint4 u6 = *(const uint4*)(Hb + (size_t)s6 * DIM + q * 8);
            uint4 u7 = *(const uint4*)(Hb + (size_t)s7 * DIM + q * 8);
            if (SRCDIS) {
                float d0 = dis[s0], d1 = dis[s1], d2 = dis[s2], d3 = dis[s3];
                float d4 = dis[s4], d5 = dis[s5], d6 = dis[s6], d7 = dis[s7];
                acc8(acc, u0, d0); acc8(acc, u1, d1);
                acc8(acc, u2, d2); acc8(acc, u3, d3);
                acc8(acc, u4, d4); acc8(acc, u5, d5);
                acc8(acc, u6, d6); acc8(acc, u7, d7);
            } else {
                acc8p(acc, u0); acc8p(acc, u1); acc8p(acc, u2); acc8p(acc, u3);
                acc8p(acc, u4); acc8p(acc, u5); acc8p(acc, u6); acc8p(acc, u7);
            }
        }
        for (; e + 4 <= e1; e += 4) {      // 4 rows in flight
            uint32_t s0 = scol[e],     s1 = scol[e + 1];
            uint32_t s2 = scol[e + 2], s3 = scol[e + 3];
            uint4 u0 = *(const uint4*)(Hb + (size_t)s0 * DIM + q * 8);
            uint4 u1 = *(const uint4*)(Hb + (size_t)s1 * DIM + q * 8);
            uint4 u2 = *(const uint4*)(Hb + (size_t)s2 * DIM + q * 8);
            uint4 u3 = *(const uint4*)(Hb + (size_t)s3 * DIM + q * 8);
            if (SRCDIS) {
                float d0 = dis[s0], d1 = dis[s1], d2 = dis[s2], d3 = dis[s3];
                acc8(acc, u0, d0); acc8(acc, u1, d1);
                acc8(acc, u2, d2); acc8(acc, u3, d3);
            } else {
                acc8p(acc, u0); acc8p(acc, u1); acc8p(acc, u2); acc8p(acc, u3);
            }
        }
        for (; e < e1; ++e) {
            uint32_t s0 = scol[e];
            uint4 u0 = *(const uint4*)(Hb + (size_t)s0 * DIM + q * 8);
            if (SRCDIS) acc8(acc, u0, dis[s0]);
            else        acc8p(acc, u0);
        }
    } else {
        for (; e < e1; ++e) {
            uint32_t s0 = col16[eLo + e];
            uint4 u0 = *(const uint4*)(Hb + (size_t)s0 * DIM + q * 8);
            if (SRCDIS) acc8(acc, u0, dis[s0]);
            else        acc8p(acc, u0);
        }
    }

    int cbase = q * 8;
    uint32_t ibase = (uint32_t)(v * DIM + cbase);
    if (CLS == 0) {
        ushort8_t o;
        #pragma unroll
        for (int j = 0; j < 8; ++j) {
            float z = acc[j] * dv + bias[cbase + j];
            z = (z >= 0.f) ? z : 0.01f * z;
            z *= drop_scale(kk0, kk1, ibase + j);
            o[j] = f2bf_rne(z);
        }
        *((ushort8_t*)(OUTb + (size_t)v * DIM + cbase)) = o;  // 256B/node row
    } else {
        float o0 = 0.f, o1 = 0.f;
        #pragma unroll
        for (int j = 0; j < 8; ++j) {
            float z = acc[j] * dv + bias[cbase + j];
            z = (z >= 0.f) ? z : 0.01f * z;
            z *= drop_scale(kk0, kk1, ibase + j);
            o0 += z * W3[(cbase + j) * 2 + 0];
            o1 += z * W3[(cbase + j) * 2 + 1];
        }
        // reduce the 16 q-lanes (consecutive lanes, same node)
        o0 += __shfl_xor(o0, 1); o0 += __shfl_xor(o0, 2);
        o0 += __shfl_xor(o0, 4); o0 += __shfl_xor(o0, 8);
        o1 += __shfl_xor(o1, 1); o1 += __shfl_xor(o1, 2);
        o1 += __shfl_xor(o1, 4); o1 += __shfl_xor(o1, 8);
        if (q == 0) {
            atomicAdd(&h3s[v * 2 + 0], o0 * dv);   // src-side dis for layer 3
            atomicAdd(&h3s[v * 2 + 1], o1 * dv);
        }
    }
}

// ---------------- layer-2 MFMA GEMM launcher (dis-prescaled output) ----------
__global__ __launch_bounds__(256) void k_gemm_bf16(const ushort* __restrict__ Xb,
                                                   const ushort* __restrict__ Wt,
                                                   const float* __restrict__ dis,
                                                   ushort* __restrict__ Hb) {
    gemm_body<0, 1>(Xb, nullptr, Wt, dis, Hb, blockIdx.x, threadIdx.x);
}

// ---------------- fused layer-3 gather + bias + log_softmax, LDS-staged ------
// 2 lanes/node (alternate edges) halves the divergent serial loop; shfl_xor(1)
// combines the two partials.
__global__ __launch_bounds__(256) void k_gather3(const uint32_t* __restrict__ row,
                                                 const ushort* __restrict__ col16,
                                                 const float* __restrict__ dis,
                                                 const float* __restrict__ H3s,
                                                 const float* __restrict__ b3,
                                                 float* __restrict__ out) {
    __shared__ ushort scol[G3CAP];
    __shared__ uint32_t srow[G3NODES + 1];
    int tid = threadIdx.x;
    int nbase = blockIdx.x * G3NODES;
    int nend = nbase + G3NODES; if (nend > N_NODES) nend = N_NODES;
    int nloc = nend - nbase;
    for (int i = tid; i <= nloc; i += 256) srow[i] = row[nbase + i];
    __syncthreads();
    uint32_t eLo = srow[0];
    uint32_t count = srow[nloc] - eLo;
    bool staged = count <= G3CAP;
    if (staged) {
        for (uint32_t i = tid; i < count; i += 256) scol[i] = col16[eLo + i];
    }
    __syncthreads();

    int nl = tid >> 1;                 // node in block
    int par = tid & 1;                 // edge-parity lane
    int v = nbase + nl;
    if (v >= N_NODES) return;
    const float2* H2 = (const float2*)H3s;
    float z0 = 0.f, z1 = 0.f;
    if (par == 0) {                    // self term once
        float2 h = H2[v];
        z0 = h.x; z1 = h.y;
    }
    uint32_t e0 = srow[nl] - eLo, e1 = srow[nl + 1] - eLo;
    if (staged) {
        for (uint32_t e = e0 + par; e < e1; e += 2) {
            float2 ha = H2[scol[e]];
            z0 += ha.x; z1 += ha.y;
        }
    } else {
        for (uint32_t e = e0 + par; e < e1; e += 2) {
            float2 ha = H2[col16[eLo + e]];
            z0 += ha.x; z1 += ha.y;
        }
    }
    z0 += __shfl_xor(z0, 1);
    z1 += __shfl_xor(z1, 1);
    if (par) return;
    float dv = dis[v];
    z0 = z0 * dv + b3[0];
    z1 = z1 * dv + b3[1];
    float m = fmaxf(z0, z1);
    float lse = m + logf(expf(z0 - m) + expf(z1 - m));
    out[v * 2 + 0] = z0 - lse;
    out[v * 2 + 1] = z1 - lse;
}

extern "C" void kernel_launch(void* const* d_in, const int* in_sizes, int n_in,
                              void* d_out, int out_size, void* d_ws, size_t ws_size,
                              hipStream_t stream) {
    const float* x  = (const float*)d_in[0];
    const int*   ei = (const int*)d_in[1];
    const float* W1 = (const float*)d_in[2];
    const float* b1 = (const float*)d_in[3];
    const float* W2 = (const float*)d_in[4];
    const float* b2 = (const float*)d_in[5];
    const float* W3 = (const float*)d_in[6];
    const float* b3 = (const float*)d_in[7];
    float* out = (float*)d_out;

    const int* src = ei;
    const int* dst = ei + N_EDGES;

    // workspace layout (u32 units) -- all regions disjoint (R10 lesson)
    uint32_t* wsu = (uint32_t*)d_ws;
    float*    wsf = (float*)d_ws;
    uint32_t* gcur   = wsu;                       // [0, 196) -> pad 256
    uint32_t* row    = wsu + 256;                 // [256, 50257) -> pad 50304
    float*    dis    = wsf + 50304;               // [50304, 100304) -> pad 100352
    uint32_t* packed = wsu + 100352;              // 196*8192 -> [100352, 1705984)
    ushort*   col16  = (ushort*)(wsu + 1705984);  // 800000 u16 -> pad to 2106112
    ushort*   Hb     = (ushort*)(wsu + 2106112);  // [2106112, 5306112)
    ushort*   Bb     = (ushort*)(wsu + 8506112);  // [8506112, 11706112)
    ushort*   W1t    = (ushort*)(wsu + 11706112); // [11706112, 11714304)
    ushort*   W2t    = (ushort*)(wsu + 11714304); // [11714304, 11722496)
    float*    h3s    = wsf + 11722496;            // [11722496, 11822496)

    // dropout keys: threefry-partitionable fold-like split of key(42) (verified R0)
    uint32_t k1a, k1b, k2a, k2b;
    threefry2x32(0u, 42u, 0u, 0u, k1a, k1b);
    threefry2x32(0u, 42u, 0u, 1u, k2a, k2b);

    hipMemsetAsync(gcur, 0, 256 * sizeof(uint32_t), stream);

    // ---- A: scatter (first!) | W transpose | h3s zero ----
    k_prep<<<NBLK + 128 + ZBLK, 256, 0, stream>>>(W1, W2, W1t, W2t,
                                                  src, dst, gcur, packed, h3s);

    // ---- CSR fill (csr blocks) OVERLAPPED with layer-1 GEMM (gemm blocks) ----
    k_fill<<<NB + 391, 256, 0, stream>>>(gcur, packed, row, dis, col16,
                                         x, W1t, Hb);

    // ---- layer 1 gather (applies dis[s] per edge since Hb is unscaled) ----
    k_gather_t<0, 1><<<GGRID, 256, 0, stream>>>(row, col16, dis, Hb, b1, Bb,
                                                nullptr, nullptr, k1a, k1b);

    // ---- layer 2 GEMM (dis-prescaled) + gather with fused classifier ----
    k_gemm_bf16<<<(N_NODES + 127) / 128, 256, 0, stream>>>(Bb, W2t, dis, Hb);
    k_gather_t<1, 0><<<GGRID, 256, 0, stream>>>(row, col16, dis, Hb, b2, nullptr,
                                                W3, h3s, k2a, k2b);

    // ---- layer 3 aggregate + log_softmax ----
    k_gather3<<<(N_NODES + G3NODES - 1) / G3NODES, 256, 0, stream>>>(row, col16, dis,
                                                                     h3s, b3, out);
}

// Round 7
// 212.702 us; speedup vs baseline: 1.1447x; 1.0054x over previous
//
#include <hip/hip_runtime.h>
#include <stdint.h>

#define N_NODES 50000
#define N_EDGES 800000
#define DIM     128
#define NB   196                 // dst buckets: dst>>8
#define CAP  8192                // fixed slots per bucket in 'packed'
#define CHUNK 2048               // edges per scatter block
#define NBLK 391                 // ceil(800000/2048)
#define GNODES 16                // nodes per gather2 block (50000 = 16*3125)
#define GGRID 3125
#define GCAP 2048                // LDS edge cap per gather2 block (mean 256)
#define FN   64                  // nodes per fused gather1+gemm2 block
#define FBLK 782                 // ceil(50000/64)
#define GCAP_F 3072              // LDS edge cap per fused block (mean 1024)
#define G3NODES 128              // nodes per gather3 block (2 lanes/node)
#define G3CAP 4096               // LDS edge cap for gather3 blocks (mean 2048)
#define ZBLK 98                  // h3s zero blocks: 25000 f32x4 / 256

typedef __attribute__((ext_vector_type(8))) unsigned short ushort8_t;
typedef __attribute__((ext_vector_type(8))) short bfrag;    // 8 bf16 = 4 VGPR
typedef __attribute__((ext_vector_type(4))) float f32x4;

// ---------------- Threefry-2x32 (exact JAX 20-round) ----------------
__host__ __device__ inline void threefry2x32(uint32_t k0, uint32_t k1,
                                             uint32_t x0, uint32_t x1,
                                             uint32_t& o0, uint32_t& o1) {
    uint32_t ks0 = k0, ks1 = k1, ks2 = k0 ^ k1 ^ 0x1BD11BDAu;
    uint32_t v0 = x0 + ks0, v1 = x1 + ks1;
#define TF_R(r) { v0 += v1; v1 = (v1 << (r)) | (v1 >> (32 - (r))); v1 ^= v0; }
    TF_R(13) TF_R(15) TF_R(26) TF_R(6)
    v0 += ks1; v1 += ks2 + 1u;
    TF_R(17) TF_R(29) TF_R(16) TF_R(24)
    v0 += ks2; v1 += ks0 + 2u;
    TF_R(13) TF_R(15) TF_R(26) TF_R(6)
    v0 += ks0; v1 += ks1 + 3u;
    TF_R(17) TF_R(29) TF_R(16) TF_R(24)
    v0 += ks1; v1 += ks2 + 4u;
    TF_R(13) TF_R(15) TF_R(26) TF_R(6)
    v0 += ks2; v1 += ks0 + 5u;
#undef TF_R
    o0 = v0; o1 = v1;
}

__device__ inline float drop_scale(uint32_t kk0, uint32_t kk1, uint32_t i) {
    uint32_t b0, b1;
    threefry2x32(kk0, kk1, 0u, i, b0, b1);
    uint32_t bits = b0 ^ b1;               // partitionable 32-bit path (verified R0)
    return (bits >> 31) ? 0.0f : 2.0f;     // keep iff u < 0.5 iff top bit 0
}

__device__ inline float bf2f(ushort u) {
    return __uint_as_float(((uint32_t)u) << 16);
}
__device__ inline float bfpair_lo(uint32_t u) { return __uint_as_float(u << 16); }
__device__ inline float bfpair_hi(uint32_t u) { return __uint_as_float(u & 0xffff0000u); }

__device__ inline ushort f2bf_rne(float f) {
    uint32_t bits = __float_as_uint(f);
    uint32_t lsb = (bits >> 16) & 1u;
    bits += 0x7fffu + lsb;                 // round-to-nearest-even
    return (ushort)(bits >> 16);
}

// 8-feat accumulate from a uint4 of bf16 pairs (dword-wise unpack: 1 VALU/elem)
__device__ inline void acc8(float* acc, uint4 u, float d) {
    acc[0] += d * bfpair_lo(u.x); acc[1] += d * bfpair_hi(u.x);
    acc[2] += d * bfpair_lo(u.y); acc[3] += d * bfpair_hi(u.y);
    acc[4] += d * bfpair_lo(u.z); acc[5] += d * bfpair_hi(u.z);
    acc[6] += d * bfpair_lo(u.w); acc[7] += d * bfpair_hi(u.w);
}
__device__ inline void acc8p(float* acc, uint4 u) {
    acc[0] += bfpair_lo(u.x); acc[1] += bfpair_hi(u.x);
    acc[2] += bfpair_lo(u.y); acc[3] += bfpair_hi(u.y);
    acc[4] += bfpair_lo(u.z); acc[5] += bfpair_hi(u.z);
    acc[6] += bfpair_lo(u.w); acc[7] += bfpair_hi(u.w);
}

// ---------------- MFMA GEMM body (layer-1 inside k_fill): Hb[v][128] --------
// F32A=1: A read from fp32, converted in registers. SCALE=0: raw output
// (dis not ready while csr blocks run; gather applies dis[s] per edge).
template<int F32A, int SCALE>
__device__ inline void gemm_body(const ushort* __restrict__ Xb,
                                 const float* __restrict__ Xf,
                                 const ushort* __restrict__ Wt,
                                 const float* __restrict__ dis,
                                 ushort* __restrict__ Hb, int gb, int tid) {
    int w = tid >> 6, lane = tid & 63;
    int m0 = gb * 128 + w * 32;
    int lrow = lane & 15, quad = lane >> 4;
    f32x4 acc[2][8] = {};
    for (int kt = 0; kt < DIM; kt += 32) {
        bfrag a[2], b[8];
        #pragma unroll
        for (int t = 0; t < 2; ++t) {
            int m = m0 + t * 16 + lrow;
            if (m >= N_NODES) m = 0;
            if (F32A) {
                const float* p = Xf + (size_t)m * DIM + kt + quad * 8;
                f32x4 v0 = *(const f32x4*)p;
                f32x4 v1 = *(const f32x4*)(p + 4);
                #pragma unroll
                for (int j = 0; j < 4; ++j) {
                    a[t][j]     = (short)f2bf_rne(v0[j]);
                    a[t][j + 4] = (short)f2bf_rne(v1[j]);
                }
            } else {
                a[t] = *(const bfrag*)(Xb + (size_t)m * DIM + kt + quad * 8);
            }
        }
        #pragma unroll
        for (int c = 0; c < 8; ++c) {
            int n = c * 16 + lrow;
            b[c] = *(const bfrag*)(Wt + (size_t)n * DIM + kt + quad * 8);
        }
        #pragma unroll
        for (int t = 0; t < 2; ++t)
            #pragma unroll
            for (int c = 0; c < 8; ++c)
                acc[t][c] = __builtin_amdgcn_mfma_f32_16x16x32_bf16(a[t], b[c], acc[t][c], 0, 0, 0);
    }
    #pragma unroll
    for (int t = 0; t < 2; ++t) {
        #pragma unroll
        for (int r = 0; r < 4; ++r) {
            int rowi = m0 + t * 16 + quad * 4 + r;
            if (rowi < N_NODES) {
                float dv = SCALE ? dis[rowi] : 1.0f;
                #pragma unroll
                for (int c = 0; c < 8; ++c) {
                    int feat = c * 16 + lrow;
                    float z = SCALE ? acc[t][c][r] * dv : acc[t][c][r];
                    Hb[(size_t)rowi * DIM + feat] = f2bf_rne(z);
                }
            }
        }
    }
}

// ---- k_prep: scatter FIRST (R18: latency-bound blocks at t=0), then W
// transposes, then h3s zeroing (folds away a memset dispatch).
__global__ __launch_bounds__(256) void k_prep(const float* __restrict__ W1,
                                              const float* __restrict__ W2,
                                              ushort* __restrict__ W1t,
                                              ushort* __restrict__ W2t,
                                              const int* __restrict__ src,
                                              const int* __restrict__ dst,
                                              uint32_t* __restrict__ gcur,
                                              uint32_t* __restrict__ packed,
                                              float* __restrict__ h3s) {
    __shared__ uint32_t h[NB];
    int b = blockIdx.x;
    int t = threadIdx.x;
    if (b < NBLK) {
        uint32_t dc[CHUNK / 256], sc[CHUNK / 256];   // static-indexed reg cache
        if (t < NB) h[t] = 0u;
        __syncthreads();
        int base = b * CHUNK;
        #pragma unroll
        for (int i = 0; i < CHUNK / 256; ++i) {
            int e = base + i * 256 + t;
            if (e < N_EDGES) {
                dc[i] = (uint32_t)dst[e];
                sc[i] = (uint32_t)src[e];
                atomicAdd(&h[dc[i] >> 8], 1u);
            } else {
                dc[i] = 0xffffffffu;
            }
        }
        __syncthreads();
        if (t < NB) {
            uint32_t c = h[t];
            h[t] = c ? atomicAdd(&gcur[t], c) : 0u;   // reserve contiguous run
        }
        __syncthreads();
        #pragma unroll
        for (int i = 0; i < CHUNK / 256; ++i) {
            if (dc[i] != 0xffffffffu) {
                uint32_t d = dc[i];
                uint32_t s = sc[i];
                uint32_t bk = d >> 8;
                uint32_t pos = atomicAdd(&h[bk], 1u);
                if (pos < CAP)
                    packed[(size_t)bk * CAP + pos] = ((d & 255u) << 16) | s;
            }
        }
    } else if (b < NBLK + 128) {
        int j = (b - NBLK) * 256 + t;              // 0..32767
        const float* W = (j < DIM * DIM) ? W1 : W2;
        ushort* Wt = (j < DIM * DIM) ? W1t : W2t;
        int i = j & (DIM * DIM - 1);
        int k = i >> 7, n = i & 127;
        Wt[n * DIM + k] = f2bf_rne(W[k * DIM + n]);
    } else {
        int idx = (b - NBLK - 128) * 256 + t;      // zero h3s (25000 f32x4)
        if (idx < (N_NODES * 2) / 4) {
            f32x4 z = {0.f, 0.f, 0.f, 0.f};
            ((f32x4*)h3s)[idx] = z;
        }
    }
}

// ---- k_fill: csr blocks (0..195, latency-bound, start at t=0) build the
// compact CSR + dis; gemm blocks (196..586) run layer-1 GEMM concurrently
// (reads only x/W1t — no dependence on csr output; writes UNSCALED Hb).
__global__ __launch_bounds__(256) void k_fill(const uint32_t* __restrict__ gcur,
                                              const uint32_t* __restrict__ packed,
                                              uint32_t* __restrict__ row,
                                              float* __restrict__ dis,
                                              ushort* __restrict__ col16,
                                              const float* __restrict__ x,
                                              const ushort* __restrict__ W1t,
                                              ushort* __restrict__ Hb) {
    __shared__ uint32_t sdeg[256];
    __shared__ uint32_t scan[256];
    __shared__ uint32_t cur[256];
    int b = blockIdx.x;
    int t = threadIdx.x;
    if (b >= NB) {                                  // layer-1 GEMM flavor
        gemm_body<1, 0>(nullptr, x, W1t, nullptr, Hb, b - NB, t);
        return;
    }
    uint32_t n = gcur[b];
    scan[t] = (t < b) ? gcur[t] : 0u;              // b <= 195 < 256
    __syncthreads();
    for (int off = 1; off < 256; off <<= 1) {
        uint32_t xx = (t >= off) ? scan[t - off] : 0u;
        __syncthreads();
        scan[t] += xx;
        __syncthreads();
    }
    uint32_t cbase = scan[255];
    __syncthreads();
    uint32_t pbase = (uint32_t)b * CAP;
    sdeg[t] = 0u;
    __syncthreads();
    for (uint32_t i = t; i < n; i += 256) {
        uint32_t u = packed[pbase + i];
        atomicAdd(&sdeg[u >> 16], 1u);
    }
    __syncthreads();
    uint32_t myd = sdeg[t];
    scan[t] = myd;
    __syncthreads();
    for (int off = 1; off < 256; off <<= 1) {
        uint32_t xx = (t >= off) ? scan[t - off] : 0u;
        __syncthreads();
        scan[t] += xx;
        __syncthreads();
    }
    uint32_t excl = scan[t] - myd;
    cur[t] = excl;
    int v = b * 256 + t;
    if (v <= N_NODES) row[v] = cbase + excl;       // compact; row[50000]=800000
    if (v < N_NODES)  dis[v] = 1.0f / sqrtf((float)(myd + 1u));
    __syncthreads();
    for (uint32_t i = t; i < n; i += 256) {        // re-read: L1-hot, no scratch
        uint32_t u = packed[pbase + i];
        uint32_t pos = cbase + atomicAdd(&cur[u >> 16], 1u);
        col16[pos] = (ushort)(u & 0xffffu);
    }
}

// ---------------- FUSED gather1 + gemm2 --------------------------------------
// Block b = 64 nodes [64b, 64b+64). Phase 1: R6-best gather structure
// (4 sub-rounds x 16 nodes, 16 lanes/node, 8/4/1 MLP cascade) + bias/leaky/
// dropout, post-activation rows -> Bs (scratch, global). __syncthreads()
// (drains vmcnt). Phase 2: 64-row MFMA GEMM: A = OWN tile rows from Bs
// (L2-hot, same-CU -> no cross-XCD coherence hazard), B = W2t; output Hb2
// dis-prescaled. GEMM-2 tile t depends ONLY on rows this block gathered ->
// no cross-block sync needed. 2 half-passes of 4 c-tiles cap acc VGPRs.
__global__ __launch_bounds__(256) void k_fused(const uint32_t* __restrict__ row,
                                               const ushort* __restrict__ col16,
                                               const float* __restrict__ dis,
                                               const ushort* __restrict__ Hb,
                                               const float* __restrict__ bias,
                                               ushort* __restrict__ Bs,
                                               const ushort* __restrict__ W2t,
                                               ushort* __restrict__ Hb2,
                                               uint32_t kk0, uint32_t kk1) {
    __shared__ ushort scol[GCAP_F];
    __shared__ uint32_t srow[FN + 1];
    int tid = threadIdx.x;
    int nbase = blockIdx.x * FN;
    int top = N_NODES - nbase; if (top > FN) top = FN;   // valid local rows
    for (int i = tid; i <= top; i += 256) srow[i] = row[nbase + i];
    __syncthreads();
    uint32_t eLo = srow[0];
    uint32_t count = srow[top] - eLo;
    bool staged = count <= GCAP_F;
    if (staged) {
        for (uint32_t i = tid; i < count; i += 256) scol[i] = col16[eLo + i];
    }
    __syncthreads();

    // ---- phase 1: gather (layer-1 aggregation, SRCDIS semantics) ----
    int nl = tid >> 4;                 // node-in-subround (0..15)
    int q  = tid & 15;                 // 8-feat slice (0..15)
    #pragma unroll
    for (int r = 0; r < 4; ++r) {
        int lr = r * 16 + nl;          // local row 0..63
        int v = nbase + lr;
        if (lr < top) {
            float dv = dis[v];
            float acc[8];
            {
                uint4 u = *(const uint4*)(Hb + (size_t)v * DIM + q * 8);
                acc[0] = bfpair_lo(u.x); acc[1] = bfpair_hi(u.x);
                acc[2] = bfpair_lo(u.y); acc[3] = bfpair_hi(u.y);
                acc[4] = bfpair_lo(u.z); acc[5] = bfpair_hi(u.z);
                acc[6] = bfpair_lo(u.w); acc[7] = bfpair_hi(u.w);
                #pragma unroll
                for (int j = 0; j < 8; ++j) acc[j] *= dv;   // self-loop
            }
            uint32_t e0 = srow[lr] - eLo, e1 = srow[lr + 1] - eLo;
            uint32_t e = e0;
            if (staged) {
                for (; e + 8 <= e1; e += 8) {      // 8 rows in flight (MLP)
                    uint32_t s0 = scol[e],     s1 = scol[e + 1];
                    uint32_t s2 = scol[e + 2], s3 = scol[e + 3];
                    uint32_t s4 = scol[e + 4], s5 = scol[e + 5];
                    uint32_t s6 = scol[e + 6], s7 = scol[e + 7];
                    uint4 u0 = *(const uint4*)(Hb + (size_t)s0 * DIM + q * 8);
                    uint4 u1 = *(const uint4*)(Hb + (size_t)s1 * DIM + q * 8);
                    uint4 u2 = *(const uint4*)(Hb + (size_t)s2 * DIM + q * 8);
                    uint4 u3 = *(const uint4*)(Hb + (size_t)s3 * DIM + q * 8);
                    uint4 u4 = *(const uint4*)(Hb + (size_t)s4 * DIM + q * 8);
                    uint4 u5 = *(const uint4*)(Hb + (size_t)s5 * DIM + q * 8);
                    uint4 u6 = *(const uint4*)(Hb + (size_t)s6 * DIM + q * 8);
                    uint4 u7 = *(const uint4*)(Hb + (size_t)s7 * DIM + q * 8);
                    float d0 = dis[s0], d1 = dis[s1], d2 = dis[s2], d3 = dis[s3];
                    float d4 = dis[s4], d5 = dis[s5], d6 = dis[s6], d7 = dis[s7];
                    acc8(acc, u0, d0); acc8(acc, u1, d1);
                    acc8(acc, u2, d2); acc8(acc, u3, d3);
                    acc8(acc, u4, d4); acc8(acc, u5, d5);
                    acc8(acc, u6, d6); acc8(acc, u7, d7);
                }
                for (; e + 4 <= e1; e += 4) {
                    uint32_t s0 = scol[e],     s1 = scol[e + 1];
                    uint32_t s2 = scol[e + 2], s3 = scol[e + 3];
                    uint4 u0 = *(const uint4*)(Hb + (size_t)s0 * DIM + q * 8);
                    uint4 u1 = *(const uint4*)(Hb + (size_t)s1 * DIM + q * 8);
                    uint4 u2 = *(const uint4*)(Hb + (size_t)s2 * DIM + q * 8);
                    uint4 u3 = *(const uint4*)(Hb + (size_t)s3 * DIM + q * 8);
                    float d0 = dis[s0], d1 = dis[s1], d2 = dis[s2], d3 = dis[s3];
                    acc8(acc, u0, d0); acc8(acc, u1, d1);
                    acc8(acc, u2, d2); acc8(acc, u3, d3);
                }
                for (; e < e1; ++e) {
                    uint32_t s0 = scol[e];
                    uint4 u0 = *(const uint4*)(Hb + (size_t)s0 * DIM + q * 8);
                    acc8(acc, u0, dis[s0]);
                }
            } else {
                for (; e < e1; ++e) {
                    uint32_t s0 = col16[eLo + e];
                    uint4 u0 = *(const uint4*)(Hb + (size_t)s0 * DIM + q * 8);
                    acc8(acc, u0, dis[s0]);
                }
            }
            int cbase = q * 8;
            uint32_t ibase = (uint32_t)(v * DIM + cbase);
            ushort8_t o;
            #pragma unroll
            for (int j = 0; j < 8; ++j) {
                float z = acc[j] * dv + bias[cbase + j];
                z = (z >= 0.f) ? z : 0.01f * z;
                z *= drop_scale(kk0, kk1, ibase + j);
                o[j] = f2bf_rne(z);
            }
            *((ushort8_t*)(Bs + (size_t)v * DIM + cbase)) = o;
        }
    }
    __syncthreads();   // all Bs rows of this tile visible (vmcnt drained)

    // ---- phase 2: 64-row GEMM: Hb2[tile] = (Bs[tile] @ W2) * dis ----
    int w = tid >> 6, lane = tid & 63;
    int lrow = lane & 15, quad = lane >> 4;
    int m = nbase + w * 16 + lrow;
    const ushort* Arow = Bs + (size_t)m * DIM;      // OOB rows read scratch: guarded below
    #pragma unroll
    for (int half = 0; half < 2; ++half) {
        f32x4 acc[4] = {};
        for (int kt = 0; kt < DIM; kt += 32) {
            bfrag a = *(const bfrag*)(Arow + kt + quad * 8);
            #pragma unroll
            for (int c = 0; c < 4; ++c) {
                int n = (half * 4 + c) * 16 + lrow;
                bfrag b = *(const bfrag*)(W2t + (size_t)n * DIM + kt + quad * 8);
                acc[c] = __builtin_amdgcn_mfma_f32_16x16x32_bf16(a, b, acc[c], 0, 0, 0);
            }
        }
        #pragma unroll
        for (int rr = 0; rr < 4; ++rr) {
            int rowi = nbase + w * 16 + quad * 4 + rr;
            if (rowi < N_NODES) {
                float dvv = dis[rowi];
                #pragma unroll
                for (int c = 0; c < 4; ++c) {
                    int feat = (half * 4 + c) * 16 + lrow;
                    Hb2[(size_t)rowi * DIM + feat] = f2bf_rne(acc[c][rr] * dvv);
                }
            }
        }
    }
}

// ---------------- gather2: aggregation + bias + leaky + dropout + classifier -
// R6-best structure: block = 16 nodes, 16 lanes/node, 8/4/1 cascade.
// SRCDIS=0: Hb2 rows are dis-prescaled. Classifier: 128->2 dot folded in,
// 16-lane shfl reduce, one atomic pair per node into h3s.
__global__ __launch_bounds__(256) void k_gather2(const uint32_t* __restrict__ row,
                                                 const ushort* __restrict__ col16,
                                                 const float* __restrict__ dis,
                                                 const ushort* __restrict__ Hb,
                                                 const float* __restrict__ bias,
                                                 const float* __restrict__ W3,
                                                 float* __restrict__ h3s,
                                                 uint32_t kk0, uint32_t kk1) {
    __shared__ ushort scol[GCAP];
    __shared__ uint32_t srow[GNODES + 1];
    int tid = threadIdx.x;
    int nbase = blockIdx.x * GNODES;
    if (tid <= GNODES) srow[tid] = row[nbase + tid];
    __syncthreads();
    uint32_t eLo = srow[0];
    uint32_t count = srow[GNODES] - eLo;
    bool staged = count <= GCAP;
    if (staged) {
        for (uint32_t i = tid; i < count; i += 256) scol[i] = col16[eLo + i];
    }
    __syncthreads();

    int nl = tid >> 4;                 // node in block (0..15)
    int q  = tid & 15;                 // 8-feat slice (0..15)
    int v = nbase + nl;                // always < N_NODES (50000 = 16*3125)
    float dv = dis[v];
    float acc[8];
    {
        uint4 u = *(const uint4*)(Hb + (size_t)v * DIM + q * 8);
        acc[0] = bfpair_lo(u.x); acc[1] = bfpair_hi(u.x);
        acc[2] = bfpair_lo(u.y); acc[3] = bfpair_hi(u.y);
        acc[4] = bfpair_lo(u.z); acc[5] = bfpair_hi(u.z);
        acc[6] = bfpair_lo(u.w); acc[7] = bfpair_hi(u.w);
    }

    uint32_t e0 = srow[nl] - eLo, e1 = srow[nl + 1] - eLo;
    uint32_t e = e0;
    if (staged) {
        for (; e + 8 <= e1; e += 8) {
            uint32_t s0 = scol[e],     s1 = scol[e + 1];
            uint32_t s2 = scol[e + 2], s3 = scol[e + 3];
            uint32_t s4 = scol[e + 4], s5 = scol[e + 5];
            uint32_t s6 = scol[e + 6], s7 = scol[e + 7];
            uint4 u0 = *(const uint4*)(Hb + (size_t)s0 * DIM + q * 8);
            uint4 u1 = *(const uint4*)(Hb + (size_t)s1 * DIM + q * 8);
            uint4 u2 = *(const uint4*)(Hb + (size_t)s2 * DIM + q * 8);
            uint4 u3 = *(const uint4*)(Hb + (size_t)s3 * DIM + q * 8);
            uint4 u4 = *(const uint4*)(Hb + (size_t)s4 * DIM + q * 8);
            uint4 u5 = *(const uint4*)(Hb + (size_t)s5 * DIM + q * 8);
            uint4 u6 = *(const uint4*)(Hb + (size_t)s6 * DIM + q * 8);
            uint4 u7 = *(const uint4*)(Hb + (size_t)s7 * DIM + q * 8);
            acc8p(acc, u0); acc8p(acc, u1); acc8p(acc, u2); acc8p(acc, u3);
            acc8p(acc, u4); acc8p(acc, u5); acc8p(acc, u6); acc8p(acc, u7);
        }
        for (; e + 4 <= e1; e += 4) {
            uint32_t s0 = scol[e],     s1 = scol[e + 1];
            uint32_t s2 = scol[e + 2], s3 = scol[e + 3];
            uint4 u0 = *(const uint4*)(Hb + (size_t)s0 * DIM + q * 8);
            uint4 u1 = *(const uint4*)(Hb + (size_t)s1 * DIM + q * 8);
            uint4 u2 = *(const uint4*)(Hb + (size_t)s2 * DIM + q * 8);
            uint4 u3 = *(const uint4*)(Hb + (size_t)s3 * DIM + q * 8);
            acc8p(acc, u0); acc8p(acc, u1); acc8p(acc, u2); acc8p(acc, u3);
        }
        for (; e < e1; ++e) {
            uint4 u0 = *(const uint4*)(Hb + (size_t)scol[e] * DIM + q * 8);
            acc8p(acc, u0);
        }
    } else {
        for (; e < e1; ++e) {
            uint4 u0 = *(const uint4*)(Hb + (size_t)col16[eLo + e] * DIM + q * 8);
            acc8p(acc, u0);
        }
    }

    int cbase = q * 8;
    uint32_t ibase = (uint32_t)(v * DIM + cbase);
    float o0 = 0.f, o1 = 0.f;
    #pragma unroll
    for (int j = 0; j < 8; ++j) {
        float z = acc[j] * dv + bias[cbase + j];
        z = (z >= 0.f) ? z : 0.01f * z;
        z *= drop_scale(kk0, kk1, ibase + j);
        o0 += z * W3[(cbase + j) * 2 + 0];
        o1 += z * W3[(cbase + j) * 2 + 1];
    }
    // reduce the 16 q-lanes (consecutive lanes, same node)
    o0 += __shfl_xor(o0, 1); o0 += __shfl_xor(o0, 2);
    o0 += __shfl_xor(o0, 4); o0 += __shfl_xor(o0, 8);
    o1 += __shfl_xor(o1, 1); o1 += __shfl_xor(o1, 2);
    o1 += __shfl_xor(o1, 4); o1 += __shfl_xor(o1, 8);
    if (q == 0) {
        atomicAdd(&h3s[v * 2 + 0], o0 * dv);   // src-side dis for layer 3
        atomicAdd(&h3s[v * 2 + 1], o1 * dv);
    }
}

// ---------------- fused layer-3 gather + bias + log_softmax, LDS-staged ------
// 2 lanes/node (alternate edges) halves the divergent serial loop; shfl_xor(1)
// combines the two partials.
__global__ __launch_bounds__(256) void k_gather3(const uint32_t* __restrict__ row,
                                                 const ushort* __restrict__ col16,
                                                 const float* __restrict__ dis,
                                                 const float* __restrict__ H3s,
                                                 const float* __restrict__ b3,
                                                 float* __restrict__ out) {
    __shared__ ushort scol[G3CAP];
    __shared__ uint32_t srow[G3NODES + 1];
    int tid = threadIdx.x;
    int nbase = blockIdx.x * G3NODES;
    int nend = nbase + G3NODES; if (nend > N_NODES) nend = N_NODES;
    int nloc = nend - nbase;
    for (int i = tid; i <= nloc; i += 256) srow[i] = row[nbase + i];
    __syncthreads();
    uint32_t eLo = srow[0];
    uint32_t count = srow[nloc] - eLo;
    bool staged = count <= G3CAP;
    if (staged) {
        for (uint32_t i = tid; i < count; i += 256) scol[i] = col16[eLo + i];
    }
    __syncthreads();

    int nl = tid >> 1;                 // node in block
    int par = tid & 1;                 // edge-parity lane
    int v = nbase + nl;
    if (v >= N_NODES) return;
    const float2* H2 = (const float2*)H3s;
    float z0 = 0.f, z1 = 0.f;
    if (par == 0) {                    // self term once
        float2 h = H2[v];
        z0 = h.x; z1 = h.y;
    }
    uint32_t e0 = srow[nl] - eLo, e1 = srow[nl + 1] - eLo;
    if (staged) {
        for (uint32_t e = e0 + par; e < e1; e += 2) {
            float2 ha = H2[scol[e]];
            z0 += ha.x; z1 += ha.y;
        }
    } else {
        for (uint32_t e = e0 + par; e < e1; e += 2) {
            float2 ha = H2[col16[eLo + e]];
            z0 += ha.x; z1 += ha.y;
        }
    }
    z0 += __shfl_xor(z0, 1);
    z1 += __shfl_xor(z1, 1);
    if (par) return;
    float dv = dis[v];
    z0 = z0 * dv + b3[0];
    z1 = z1 * dv + b3[1];
    float m = fmaxf(z0, z1);
    float lse = m + logf(expf(z0 - m) + expf(z1 - m));
    out[v * 2 + 0] = z0 - lse;
    out[v * 2 + 1] = z1 - lse;
}

extern "C" void kernel_launch(void* const* d_in, const int* in_sizes, int n_in,
                              void* d_out, int out_size, void* d_ws, size_t ws_size,
                              hipStream_t stream) {
    const float* x  = (const float*)d_in[0];
    const int*   ei = (const int*)d_in[1];
    const float* W1 = (const float*)d_in[2];
    const float* b1 = (const float*)d_in[3];
    const float* W2 = (const float*)d_in[4];
    const float* b2 = (const float*)d_in[5];
    const float* W3 = (const float*)d_in[6];
    const float* b3 = (const float*)d_in[7];
    float* out = (float*)d_out;

    const int* src = ei;
    const int* dst = ei + N_EDGES;

    // workspace layout (u32 units) -- all regions disjoint (R10 lesson)
    uint32_t* wsu = (uint32_t*)d_ws;
    float*    wsf = (float*)d_ws;
    uint32_t* gcur   = wsu;                       // [0, 196) -> pad 256
    uint32_t* row    = wsu + 256;                 // [256, 50257) -> pad 50304
    float*    dis    = wsf + 50304;               // [50304, 100304) -> pad 100352
    uint32_t* packed = wsu + 100352;              // 196*8192 -> [100352, 1705984)
    ushort*   col16  = (ushort*)(wsu + 1705984);  // 800000 u16 -> pad to 2106112
    ushort*   Hb     = (ushort*)(wsu + 2106112);  // layer-1 H  [2106112, 5306112)
    ushort*   Bs     = (ushort*)(wsu + 5306112);  // fused scratch (post-act rows)
    ushort*   Hb2    = (ushort*)(wsu + 8506112);  // layer-2 H  [8506112, 11706112)
    ushort*   W1t    = (ushort*)(wsu + 11706112); // [11706112, 11714304)
    ushort*   W2t    = (ushort*)(wsu + 11714304); // [11714304, 11722496)
    float*    h3s    = wsf + 11722496;            // [11722496, 11822496)

    // dropout keys: threefry-partitionable fold-like split of key(42) (verified R0)
    uint32_t k1a, k1b, k2a, k2b;
    threefry2x32(0u, 42u, 0u, 0u, k1a, k1b);
    threefry2x32(0u, 42u, 0u, 1u, k2a, k2b);

    hipMemsetAsync(gcur, 0, 256 * sizeof(uint32_t), stream);

    // ---- A: scatter (first!) | W transpose | h3s zero ----
    k_prep<<<NBLK + 128 + ZBLK, 256, 0, stream>>>(W1, W2, W1t, W2t,
                                                  src, dst, gcur, packed, h3s);

    // ---- CSR fill (csr blocks) OVERLAPPED with layer-1 GEMM (gemm blocks) ----
    k_fill<<<NB + 391, 256, 0, stream>>>(gcur, packed, row, dis, col16,
                                         x, W1t, Hb);

    // ---- FUSED: layer-1 gather (+bias/leaky/dropout) + layer-2 GEMM ----
    k_fused<<<FBLK, 256, 0, stream>>>(row, col16, dis, Hb, b1, Bs, W2t, Hb2,
                                      k1a, k1b);

    // ---- layer-2 gather + fused classifier ----
    k_gather2<<<GGRID, 256, 0, stream>>>(row, col16, dis, Hb2, b2, W3, h3s,
                                         k2a, k2b);

    // ---- layer 3 aggregate + log_softmax ----
    k_gather3<<<(N_NODES + G3NODES - 1) / G3NODES, 256, 0, stream>>>(row, col16, dis,
                                                                     h3s, b3, out);
}

// Round 8
// 204.194 us; speedup vs baseline: 1.1924x; 1.0417x over previous
//
#include <hip/hip_runtime.h>
#include <stdint.h>

#define N_NODES 50000
#define N_EDGES 800000
#define DIM     128
#define NB   196                 // dst buckets: dst>>8
#define CAP  8192                // fixed slots per bucket in 'packed'
#define CHUNK 2048               // edges per scatter block
#define NBLK 391                 // ceil(800000/2048)
#define GNODES 16                // nodes per gather/fused block (50000 = 16*3125)
#define GGRID 3125
#define GCAP 2048                // LDS edge cap per block (mean 256)
#define G3NODES 128              // nodes per gather3 block (2 lanes/node)
#define G3CAP 4096               // LDS edge cap for gather3 blocks (mean 2048)
#define ZBLK 98                  // h3s zero blocks: 25000 f32x4 / 256

typedef __attribute__((ext_vector_type(8))) unsigned short ushort8_t;
typedef __attribute__((ext_vector_type(8))) short bfrag;    // 8 bf16 = 4 VGPR
typedef __attribute__((ext_vector_type(4))) float f32x4;

// ---------------- Threefry-2x32 (exact JAX 20-round) ----------------
__host__ __device__ inline void threefry2x32(uint32_t k0, uint32_t k1,
                                             uint32_t x0, uint32_t x1,
                                             uint32_t& o0, uint32_t& o1) {
    uint32_t ks0 = k0, ks1 = k1, ks2 = k0 ^ k1 ^ 0x1BD11BDAu;
    uint32_t v0 = x0 + ks0, v1 = x1 + ks1;
#define TF_R(r) { v0 += v1; v1 = (v1 << (r)) | (v1 >> (32 - (r))); v1 ^= v0; }
    TF_R(13) TF_R(15) TF_R(26) TF_R(6)
    v0 += ks1; v1 += ks2 + 1u;
    TF_R(17) TF_R(29) TF_R(16) TF_R(24)
    v0 += ks2; v1 += ks0 + 2u;
    TF_R(13) TF_R(15) TF_R(26) TF_R(6)
    v0 += ks0; v1 += ks1 + 3u;
    TF_R(17) TF_R(29) TF_R(16) TF_R(24)
    v0 += ks1; v1 += ks2 + 4u;
    TF_R(13) TF_R(15) TF_R(26) TF_R(6)
    v0 += ks2; v1 += ks0 + 5u;
#undef TF_R
    o0 = v0; o1 = v1;
}

__device__ inline float drop_scale(uint32_t kk0, uint32_t kk1, uint32_t i) {
    uint32_t b0, b1;
    threefry2x32(kk0, kk1, 0u, i, b0, b1);
    uint32_t bits = b0 ^ b1;               // partitionable 32-bit path (verified R0)
    return (bits >> 31) ? 0.0f : 2.0f;     // keep iff u < 0.5 iff top bit 0
}

__device__ inline float bf2f(ushort u) {
    return __uint_as_float(((uint32_t)u) << 16);
}
__device__ inline float bfpair_lo(uint32_t u) { return __uint_as_float(u << 16); }
__device__ inline float bfpair_hi(uint32_t u) { return __uint_as_float(u & 0xffff0000u); }

__device__ inline ushort f2bf_rne(float f) {
    uint32_t bits = __float_as_uint(f);
    uint32_t lsb = (bits >> 16) & 1u;
    bits += 0x7fffu + lsb;                 // round-to-nearest-even
    return (ushort)(bits >> 16);
}

// 8-feat accumulate from a uint4 of bf16 pairs (dword-wise unpack: 1 VALU/elem)
__device__ inline void acc8(float* acc, uint4 u, float d) {
    acc[0] += d * bfpair_lo(u.x); acc[1] += d * bfpair_hi(u.x);
    acc[2] += d * bfpair_lo(u.y); acc[3] += d * bfpair_hi(u.y);
    acc[4] += d * bfpair_lo(u.z); acc[5] += d * bfpair_hi(u.z);
    acc[6] += d * bfpair_lo(u.w); acc[7] += d * bfpair_hi(u.w);
}
__device__ inline void acc8p(float* acc, uint4 u) {
    acc[0] += bfpair_lo(u.x); acc[1] += bfpair_hi(u.x);
    acc[2] += bfpair_lo(u.y); acc[3] += bfpair_hi(u.y);
    acc[4] += bfpair_lo(u.z); acc[5] += bfpair_hi(u.z);
    acc[6] += bfpair_lo(u.w); acc[7] += bfpair_hi(u.w);
}

// ---------------- MFMA GEMM body (layer-1 inside k_fill): Hb[v][128] --------
// F32A=1: A read from fp32, converted in registers. SCALE=0: raw output
// (dis not ready while csr blocks run; gather applies dis[s] per edge).
template<int F32A, int SCALE>
__device__ inline void gemm_body(const ushort* __restrict__ Xb,
                                 const float* __restrict__ Xf,
                                 const ushort* __restrict__ Wt,
                                 const float* __restrict__ dis,
                                 ushort* __restrict__ Hb, int gb, int tid) {
    int w = tid >> 6, lane = tid & 63;
    int m0 = gb * 128 + w * 32;
    int lrow = lane & 15, quad = lane >> 4;
    f32x4 acc[2][8] = {};
    for (int kt = 0; kt < DIM; kt += 32) {
        bfrag a[2], b[8];
        #pragma unroll
        for (int t = 0; t < 2; ++t) {
            int m = m0 + t * 16 + lrow;
            if (m >= N_NODES) m = 0;
            if (F32A) {
                const float* p = Xf + (size_t)m * DIM + kt + quad * 8;
                f32x4 v0 = *(const f32x4*)p;
                f32x4 v1 = *(const f32x4*)(p + 4);
                #pragma unroll
                for (int j = 0; j < 4; ++j) {
                    a[t][j]     = (short)f2bf_rne(v0[j]);
                    a[t][j + 4] = (short)f2bf_rne(v1[j]);
                }
            } else {
                a[t] = *(const bfrag*)(Xb + (size_t)m * DIM + kt + quad * 8);
            }
        }
        #pragma unroll
        for (int c = 0; c < 8; ++c) {
            int n = c * 16 + lrow;
            b[c] = *(const bfrag*)(Wt + (size_t)n * DIM + kt + quad * 8);
        }
        #pragma unroll
        for (int t = 0; t < 2; ++t)
            #pragma unroll
            for (int c = 0; c < 8; ++c)
                acc[t][c] = __builtin_amdgcn_mfma_f32_16x16x32_bf16(a[t], b[c], acc[t][c], 0, 0, 0);
    }
    #pragma unroll
    for (int t = 0; t < 2; ++t) {
        #pragma unroll
        for (int r = 0; r < 4; ++r) {
            int rowi = m0 + t * 16 + quad * 4 + r;
            if (rowi < N_NODES) {
                float dv = SCALE ? dis[rowi] : 1.0f;
                #pragma unroll
                for (int c = 0; c < 8; ++c) {
                    int feat = c * 16 + lrow;
                    float z = SCALE ? acc[t][c][r] * dv : acc[t][c][r];
                    Hb[(size_t)rowi * DIM + feat] = f2bf_rne(z);
                }
            }
        }
    }
}

// ---- k_prep: scatter FIRST (R18: latency-bound blocks at t=0), then W
// transposes, then h3s zeroing (folds away a memset dispatch).
__global__ __launch_bounds__(256) void k_prep(const float* __restrict__ W1,
                                              const float* __restrict__ W2,
                                              ushort* __restrict__ W1t,
                                              ushort* __restrict__ W2t,
                                              const int* __restrict__ src,
                                              const int* __restrict__ dst,
                                              uint32_t* __restrict__ gcur,
                                              uint32_t* __restrict__ packed,
                                              float* __restrict__ h3s) {
    __shared__ uint32_t h[NB];
    int b = blockIdx.x;
    int t = threadIdx.x;
    if (b < NBLK) {
        uint32_t dc[CHUNK / 256], sc[CHUNK / 256];   // static-indexed reg cache
        if (t < NB) h[t] = 0u;
        __syncthreads();
        int base = b * CHUNK;
        #pragma unroll
        for (int i = 0; i < CHUNK / 256; ++i) {
            int e = base + i * 256 + t;
            if (e < N_EDGES) {
                dc[i] = (uint32_t)dst[e];
                sc[i] = (uint32_t)src[e];
                atomicAdd(&h[dc[i] >> 8], 1u);
            } else {
                dc[i] = 0xffffffffu;
            }
        }
        __syncthreads();
        if (t < NB) {
            uint32_t c = h[t];
            h[t] = c ? atomicAdd(&gcur[t], c) : 0u;   // reserve contiguous run
        }
        __syncthreads();
        #pragma unroll
        for (int i = 0; i < CHUNK / 256; ++i) {
            if (dc[i] != 0xffffffffu) {
                uint32_t d = dc[i];
                uint32_t s = sc[i];
                uint32_t bk = d >> 8;
                uint32_t pos = atomicAdd(&h[bk], 1u);
                if (pos < CAP)
                    packed[(size_t)bk * CAP + pos] = ((d & 255u) << 16) | s;
            }
        }
    } else if (b < NBLK + 128) {
        int j = (b - NBLK) * 256 + t;              // 0..32767
        const float* W = (j < DIM * DIM) ? W1 : W2;
        ushort* Wt = (j < DIM * DIM) ? W1t : W2t;
        int i = j & (DIM * DIM - 1);
        int k = i >> 7, n = i & 127;
        Wt[n * DIM + k] = f2bf_rne(W[k * DIM + n]);
    } else {
        int idx = (b - NBLK - 128) * 256 + t;      // zero h3s (25000 f32x4)
        if (idx < (N_NODES * 2) / 4) {
            f32x4 z = {0.f, 0.f, 0.f, 0.f};
            ((f32x4*)h3s)[idx] = z;
        }
    }
}

// ---- k_fill: csr blocks (0..195, latency-bound, start at t=0) build the
// compact CSR + dis; gemm blocks (196..586) run layer-1 GEMM concurrently
// (reads only x/W1t — no dependence on csr output; writes UNSCALED Hb).
__global__ __launch_bounds__(256) void k_fill(const uint32_t* __restrict__ gcur,
                                              const uint32_t* __restrict__ packed,
                                              uint32_t* __restrict__ row,
                                              float* __restrict__ dis,
                                              ushort* __restrict__ col16,
                                              const float* __restrict__ x,
                                              const ushort* __restrict__ W1t,
                                              ushort* __restrict__ Hb) {
    __shared__ uint32_t sdeg[256];
    __shared__ uint32_t scan[256];
    __shared__ uint32_t cur[256];
    int b = blockIdx.x;
    int t = threadIdx.x;
    if (b >= NB) {                                  // layer-1 GEMM flavor
        gemm_body<1, 0>(nullptr, x, W1t, nullptr, Hb, b - NB, t);
        return;
    }
    uint32_t n = gcur[b];
    scan[t] = (t < b) ? gcur[t] : 0u;              // b <= 195 < 256
    __syncthreads();
    for (int off = 1; off < 256; off <<= 1) {
        uint32_t xx = (t >= off) ? scan[t - off] : 0u;
        __syncthreads();
        scan[t] += xx;
        __syncthreads();
    }
    uint32_t cbase = scan[255];
    __syncthreads();
    uint32_t pbase = (uint32_t)b * CAP;
    sdeg[t] = 0u;
    __syncthreads();
    for (uint32_t i = t; i < n; i += 256) {
        uint32_t u = packed[pbase + i];
        atomicAdd(&sdeg[u >> 16], 1u);
    }
    __syncthreads();
    uint32_t myd = sdeg[t];
    scan[t] = myd;
    __syncthreads();
    for (int off = 1; off < 256; off <<= 1) {
        uint32_t xx = (t >= off) ? scan[t - off] : 0u;
        __syncthreads();
        scan[t] += xx;
        __syncthreads();
    }
    uint32_t excl = scan[t] - myd;
    cur[t] = excl;
    int v = b * 256 + t;
    if (v <= N_NODES) row[v] = cbase + excl;       // compact; row[50000]=800000
    if (v < N_NODES)  dis[v] = 1.0f / sqrtf((float)(myd + 1u));
    __syncthreads();
    for (uint32_t i = t; i < n; i += 256) {        // re-read: L1-hot, no scratch
        uint32_t u = packed[pbase + i];
        uint32_t pos = cbase + atomicAdd(&cur[u >> 16], 1u);
        col16[pos] = (ushort)(u & 0xffffu);
    }
}

// ---------------- FUSED gather1 + gemm2, 16-node tile, LDS-staged A ----------
// Block b = 16 nodes (3125 blocks: full occupancy, R7 lesson — the fused grid
// must match the gather's TLP needs, not the GEMM's).
// Phase 1: R6-best gather (16 lanes/node, 8/4/1 MLP cascade) + bias/leaky/
// dropout -> post-activation tile in LDS (16x128 bf16 = 4KB, XOR-swizzled:
// ushort idx ^= (row&7)<<3 breaks the 256B-stride bank conflict, G4).
// Phase 2: 16-row MFMA GEMM: A from LDS tile, B = W2t; Hb2 dis-prescaled.
// No global Bs round-trip (saves 25.6MB), no cross-block dependency.
__global__ __launch_bounds__(256) void k_fused(const uint32_t* __restrict__ row,
                                               const ushort* __restrict__ col16,
                                               const float* __restrict__ dis,
                                               const ushort* __restrict__ Hb,
                                               const float* __restrict__ bias,
                                               const ushort* __restrict__ W2t,
                                               ushort* __restrict__ Hb2,
                                               uint32_t kk0, uint32_t kk1) {
    __shared__ ushort scol[GCAP];
    __shared__ uint32_t srow[GNODES + 1];
    __shared__ ushort At[GNODES * DIM];          // post-act tile, swizzled
    int tid = threadIdx.x;
    int nbase = blockIdx.x * GNODES;
    if (tid <= GNODES) srow[tid] = row[nbase + tid];
    __syncthreads();
    uint32_t eLo = srow[0];
    uint32_t count = srow[GNODES] - eLo;
    bool staged = count <= GCAP;
    if (staged) {
        for (uint32_t i = tid; i < count; i += 256) scol[i] = col16[eLo + i];
    }
    __syncthreads();

    // ---- phase 1: gather + epilogue -> LDS tile ----
    int nl = tid >> 4;                 // node in block (0..15)
    int q  = tid & 15;                 // 8-feat slice (0..15)
    int v = nbase + nl;                // always < N_NODES (50000 = 16*3125)
    float dv = dis[v];
    float acc[8];
    {
        uint4 u = *(const uint4*)(Hb + (size_t)v * DIM + q * 8);
        acc[0] = bfpair_lo(u.x); acc[1] = bfpair_hi(u.x);
        acc[2] = bfpair_lo(u.y); acc[3] = bfpair_hi(u.y);
        acc[4] = bfpair_lo(u.z); acc[5] = bfpair_hi(u.z);
        acc[6] = bfpair_lo(u.w); acc[7] = bfpair_hi(u.w);
        #pragma unroll
        for (int j = 0; j < 8; ++j) acc[j] *= dv;   // self-loop (Hb unscaled)
    }
    uint32_t e0 = srow[nl] - eLo, e1 = srow[nl + 1] - eLo;
    uint32_t e = e0;
    if (staged) {
        for (; e + 8 <= e1; e += 8) {      // 8 rows in flight (MLP)
            uint32_t s0 = scol[e],     s1 = scol[e + 1];
            uint32_t s2 = scol[e + 2], s3 = scol[e + 3];
            uint32_t s4 = scol[e + 4], s5 = scol[e + 5];
            uint32_t s6 = scol[e + 6], s7 = scol[e + 7];
            uint4 u0 = *(const uint4*)(Hb + (size_t)s0 * DIM + q * 8);
            uint4 u1 = *(const uint4*)(Hb + (size_t)s1 * DIM + q * 8);
            uint4 u2 = *(const uint4*)(Hb + (size_t)s2 * DIM + q * 8);
            uint4 u3 = *(const uint4*)(Hb + (size_t)s3 * DIM + q * 8);
            uint4 u4 = *(const uint4*)(Hb + (size_t)s4 * DIM + q * 8);
            uint4 u5 = *(const uint4*)(Hb + (size_t)s5 * DIM + q * 8);
            uint4 u6 = *(const uint4*)(Hb + (size_t)s6 * DIM + q * 8);
            uint4 u7 = *(const uint4*)(Hb + (size_t)s7 * DIM + q * 8);
            float d0 = dis[s0], d1 = dis[s1], d2 = dis[s2], d3 = dis[s3];
            float d4 = dis[s4], d5 = dis[s5], d6 = dis[s6], d7 = dis[s7];
            acc8(acc, u0, d0); acc8(acc, u1, d1);
            acc8(acc, u2, d2); acc8(acc, u3, d3);
            acc8(acc, u4, d4); acc8(acc, u5, d5);
            acc8(acc, u6, d6); acc8(acc, u7, d7);
        }
        for (; e + 4 <= e1; e += 4) {
            uint32_t s0 = scol[e],     s1 = scol[e + 1];
            uint32_t s2 = scol[e + 2], s3 = scol[e + 3];
            uint4 u0 = *(const uint4*)(Hb + (size_t)s0 * DIM + q * 8);
            uint4 u1 = *(const uint4*)(Hb + (size_t)s1 * DIM + q * 8);
            uint4 u2 = *(const uint4*)(Hb + (size_t)s2 * DIM + q * 8);
            uint4 u3 = *(const uint4*)(Hb + (size_t)s3 * DIM + q * 8);
            float d0 = dis[s0], d1 = dis[s1], d2 = dis[s2], d3 = dis[s3];
            acc8(acc, u0, d0); acc8(acc, u1, d1);
            acc8(acc, u2, d2); acc8(acc, u3, d3);
        }
        for (; e < e1; ++e) {
            uint32_t s0 = scol[e];
            uint4 u0 = *(const uint4*)(Hb + (size_t)s0 * DIM + q * 8);
            acc8(acc, u0, dis[s0]);
        }
    } else {
        for (; e < e1; ++e) {
            uint32_t s0 = col16[eLo + e];
            uint4 u0 = *(const uint4*)(Hb + (size_t)s0 * DIM + q * 8);
            acc8(acc, u0, dis[s0]);
        }
    }
    {
        int cbase = q * 8;
        uint32_t ibase = (uint32_t)(v * DIM + cbase);
        ushort8_t o;
        #pragma unroll
        for (int j = 0; j < 8; ++j) {
            float z = acc[j] * dv + bias[cbase + j];
            z = (z >= 0.f) ? z : 0.01f * z;
            z *= drop_scale(kk0, kk1, ibase + j);
            o[j] = f2bf_rne(z);
        }
        // swizzled store: idx = row*128 + (q*8 ^ ((row&7)<<3))
        *((ushort8_t*)(At + nl * DIM + ((q * 8) ^ ((nl & 7) << 3)))) = o;
    }
    __syncthreads();

    // ---- phase 2: 16-row GEMM: Hb2[tile] = (At @ W2) * dis ----
    int w = tid >> 6, lane = tid & 63;
    int lrow = lane & 15, quad = lane >> 4;
    int swz = (lrow & 7) << 3;
    f32x4 acc2[2] = {};
    for (int kt = 0; kt < DIM; kt += 32) {
        int k = kt + quad * 8;
        bfrag a = *(const bfrag*)(At + lrow * DIM + (k ^ swz));
        #pragma unroll
        for (int ct = 0; ct < 2; ++ct) {
            int n = (w * 2 + ct) * 16 + lrow;
            bfrag b = *(const bfrag*)(W2t + (size_t)n * DIM + k);
            acc2[ct] = __builtin_amdgcn_mfma_f32_16x16x32_bf16(a, b, acc2[ct], 0, 0, 0);
        }
    }
    #pragma unroll
    for (int ct = 0; ct < 2; ++ct) {
        #pragma unroll
        for (int rr = 0; rr < 4; ++rr) {
            int rowi = nbase + quad * 4 + rr;
            float dvv = dis[rowi];
            int feat = (w * 2 + ct) * 16 + lrow;
            Hb2[(size_t)rowi * DIM + feat] = f2bf_rne(acc2[ct][rr] * dvv);
        }
    }
}

// ---------------- gather2: aggregation + bias + leaky + dropout + classifier -
// R6-best structure: block = 16 nodes, 16 lanes/node, 8/4/1 cascade.
// Hb2 rows are dis-prescaled. Classifier: 128->2 dot folded in,
// 16-lane shfl reduce, one atomic pair per node into h3s.
__global__ __launch_bounds__(256) void k_gather2(const uint32_t* __restrict__ row,
                                                 const ushort* __restrict__ col16,
                                                 const float* __restrict__ dis,
                                                 const ushort* __restrict__ Hb,
                                                 const float* __restrict__ bias,
                                                 const float* __restrict__ W3,
                                                 float* __restrict__ h3s,
                                                 uint32_t kk0, uint32_t kk1) {
    __shared__ ushort scol[GCAP];
    __shared__ uint32_t srow[GNODES + 1];
    int tid = threadIdx.x;
    int nbase = blockIdx.x * GNODES;
    if (tid <= GNODES) srow[tid] = row[nbase + tid];
    __syncthreads();
    uint32_t eLo = srow[0];
    uint32_t count = srow[GNODES] - eLo;
    bool staged = count <= GCAP;
    if (staged) {
        for (uint32_t i = tid; i < count; i += 256) scol[i] = col16[eLo + i];
    }
    __syncthreads();

    int nl = tid >> 4;                 // node in block (0..15)
    int q  = tid & 15;                 // 8-feat slice (0..15)
    int v = nbase + nl;                // always < N_NODES (50000 = 16*3125)
    float dv = dis[v];
    float acc[8];
    {
        uint4 u = *(const uint4*)(Hb + (size_t)v * DIM + q * 8);
        acc[0] = bfpair_lo(u.x); acc[1] = bfpair_hi(u.x);
        acc[2] = bfpair_lo(u.y); acc[3] = bfpair_hi(u.y);
        acc[4] = bfpair_lo(u.z); acc[5] = bfpair_hi(u.z);
        acc[6] = bfpair_lo(u.w); acc[7] = bfpair_hi(u.w);
    }

    uint32_t e0 = srow[nl] - eLo, e1 = srow[nl + 1] - eLo;
    uint32_t e = e0;
    if (staged) {
        for (; e + 8 <= e1; e += 8) {
            uint32_t s0 = scol[e],     s1 = scol[e + 1];
            uint32_t s2 = scol[e + 2], s3 = scol[e + 3];
            uint32_t s4 = scol[e + 4], s5 = scol[e + 5];
            uint32_t s6 = scol[e + 6], s7 = scol[e + 7];
            uint4 u0 = *(const uint4*)(Hb + (size_t)s0 * DIM + q * 8);
            uint4 u1 = *(const uint4*)(Hb + (size_t)s1 * DIM + q * 8);
            uint4 u2 = *(const uint4*)(Hb + (size_t)s2 * DIM + q * 8);
            uint4 u3 = *(const uint4*)(Hb + (size_t)s3 * DIM + q * 8);
            uint4 u4 = *(const uint4*)(Hb + (size_t)s4 * DIM + q * 8);
            uint4 u5 = *(const uint4*)(Hb + (size_t)s5 * DIM + q * 8);
            uint4 u6 = *(const uint4*)(Hb + (size_t)s6 * DIM + q * 8);
            uint4 u7 = *(const uint4*)(Hb + (size_t)s7 * DIM + q * 8);
            acc8p(acc, u0); acc8p(acc, u1); acc8p(acc, u2); acc8p(acc, u3);
            acc8p(acc, u4); acc8p(acc, u5); acc8p(acc, u6); acc8p(acc, u7);
        }
        for (; e + 4 <= e1; e += 4) {
            uint32_t s0 = scol[e],     s1 = scol[e + 1];
            uint32_t s2 = scol[e + 2], s3 = scol[e + 3];
            uint4 u0 = *(const uint4*)(Hb + (size_t)s0 * DIM + q * 8);
            uint4 u1 = *(const uint4*)(Hb + (size_t)s1 * DIM + q * 8);
            uint4 u2 = *(const uint4*)(Hb + (size_t)s2 * DIM + q * 8);
            uint4 u3 = *(const uint4*)(Hb + (size_t)s3 * DIM + q * 8);
            acc8p(acc, u0); acc8p(acc, u1); acc8p(acc, u2); acc8p(acc, u3);
        }
        for (; e < e1; ++e) {
            uint4 u0 = *(const uint4*)(Hb + (size_t)scol[e] * DIM + q * 8);
            acc8p(acc, u0);
        }
    } else {
        for (; e < e1; ++e) {
            uint4 u0 = *(const uint4*)(Hb + (size_t)col16[eLo + e] * DIM + q * 8);
            acc8p(acc, u0);
        }
    }

    int cbase = q * 8;
    uint32_t ibase = (uint32_t)(v * DIM + cbase);
    float o0 = 0.f, o1 = 0.f;
    #pragma unroll
    for (int j = 0; j < 8; ++j) {
        float z = acc[j] * dv + bias[cbase + j];
        z = (z >= 0.f) ? z : 0.01f * z;
        z *= drop_scale(kk0, kk1, ibase + j);
        o0 += z * W3[(cbase + j) * 2 + 0];
        o1 += z * W3[(cbase + j) * 2 + 1];
    }
    // reduce the 16 q-lanes (consecutive lanes, same node)
    o0 += __shfl_xor(o0, 1); o0 += __shfl_xor(o0, 2);
    o0 += __shfl_xor(o0, 4); o0 += __shfl_xor(o0, 8);
    o1 += __shfl_xor(o1, 1); o1 += __shfl_xor(o1, 2);
    o1 += __shfl_xor(o1, 4); o1 += __shfl_xor(o1, 8);
    if (q == 0) {
        atomicAdd(&h3s[v * 2 + 0], o0 * dv);   // src-side dis for layer 3
        atomicAdd(&h3s[v * 2 + 1], o1 * dv);
    }
}

// ---------------- fused layer-3 gather + bias + log_softmax, LDS-staged ------
// 2 lanes/node (alternate edges) halves the divergent serial loop; shfl_xor(1)
// combines the two partials.
__global__ __launch_bounds__(256) void k_gather3(const uint32_t* __restrict__ row,
                                                 const ushort* __restrict__ col16,
                                                 const float* __restrict__ dis,
                                                 const float* __restrict__ H3s,
                                                 const float* __restrict__ b3,
                                                 float* __restrict__ out) {
    __shared__ ushort scol[G3CAP];
    __shared__ uint32_t srow[G3NODES + 1];
    int tid = threadIdx.x;
    int nbase = blockIdx.x * G3NODES;
    int nend = nbase + G3NODES; if (nend > N_NODES) nend = N_NODES;
    int nloc = nend - nbase;
    for (int i = tid; i <= nloc; i += 256) srow[i] = row[nbase + i];
    __syncthreads();
    uint32_t eLo = srow[0];
    uint32_t count = srow[nloc] - eLo;
    bool staged = count <= G3CAP;
    if (staged) {
        for (uint32_t i = tid; i < count; i += 256) scol[i] = col16[eLo + i];
    }
    __syncthreads();

    int nl = tid >> 1;                 // node in block
    int par = tid & 1;                 // edge-parity lane
    int v = nbase + nl;
    if (v >= N_NODES) return;
    const float2* H2 = (const float2*)H3s;
    float z0 = 0.f, z1 = 0.f;
    if (par == 0) {                    // self term once
        float2 h = H2[v];
        z0 = h.x; z1 = h.y;
    }
    uint32_t e0 = srow[nl] - eLo, e1 = srow[nl + 1] - eLo;
    if (staged) {
        for (uint32_t e = e0 + par; e < e1; e += 2) {
            float2 ha = H2[scol[e]];
            z0 += ha.x; z1 += ha.y;
        }
    } else {
        for (uint32_t e = e0 + par; e < e1; e += 2) {
            float2 ha = H2[col16[eLo + e]];
            z0 += ha.x; z1 += ha.y;
        }
    }
    z0 += __shfl_xor(z0, 1);
    z1 += __shfl_xor(z1, 1);
    if (par) return;
    float dv = dis[v];
    z0 = z0 * dv + b3[0];
    z1 = z1 * dv + b3[1];
    float m = fmaxf(z0, z1);
    float lse = m + logf(expf(z0 - m) + expf(z1 - m));
    out[v * 2 + 0] = z0 - lse;
    out[v * 2 + 1] = z1 - lse;
}

extern "C" void kernel_launch(void* const* d_in, const int* in_sizes, int n_in,
                              void* d_out, int out_size, void* d_ws, size_t ws_size,
                              hipStream_t stream) {
    const float* x  = (const float*)d_in[0];
    const int*   ei = (const int*)d_in[1];
    const float* W1 = (const float*)d_in[2];
    const float* b1 = (const float*)d_in[3];
    const float* W2 = (const float*)d_in[4];
    const float* b2 = (const float*)d_in[5];
    const float* W3 = (const float*)d_in[6];
    const float* b3 = (const float*)d_in[7];
    float* out = (float*)d_out;

    const int* src = ei;
    const int* dst = ei + N_EDGES;

    // workspace layout (u32 units) -- all regions disjoint (R10 lesson)
    uint32_t* wsu = (uint32_t*)d_ws;
    float*    wsf = (float*)d_ws;
    uint32_t* gcur   = wsu;                       // [0, 196) -> pad 256
    uint32_t* row    = wsu + 256;                 // [256, 50257) -> pad 50304
    float*    dis    = wsf + 50304;               // [50304, 100304) -> pad 100352
    uint32_t* packed = wsu + 100352;              // 196*8192 -> [100352, 1705984)
    ushort*   col16  = (ushort*)(wsu + 1705984);  // 800000 u16 -> pad to 2106112
    ushort*   Hb     = (ushort*)(wsu + 2106112);  // layer-1 H  [2106112, 5306112)
    ushort*   Hb2    = (ushort*)(wsu + 8506112);  // layer-2 H  [8506112, 11706112)
    ushort*   W1t    = (ushort*)(wsu + 11706112); // [11706112, 11714304)
    ushort*   W2t    = (ushort*)(wsu + 11714304); // [11714304, 11722496)
    float*    h3s    = wsf + 11722496;            // [11722496, 11822496)

    // dropout keys: threefry-partitionable fold-like split of key(42) (verified R0)
    uint32_t k1a, k1b, k2a, k2b;
    threefry2x32(0u, 42u, 0u, 0u, k1a, k1b);
    threefry2x32(0u, 42u, 0u, 1u, k2a, k2b);

    hipMemsetAsync(gcur, 0, 256 * sizeof(uint32_t), stream);

    // ---- A: scatter (first!) | W transpose | h3s zero ----
    k_prep<<<NBLK + 128 + ZBLK, 256, 0, stream>>>(W1, W2, W1t, W2t,
                                                  src, dst, gcur, packed, h3s);

    // ---- CSR fill (csr blocks) OVERLAPPED with layer-1 GEMM (gemm blocks) ----
    k_fill<<<NB + 391, 256, 0, stream>>>(gcur, packed, row, dis, col16,
                                         x, W1t, Hb);

    // ---- FUSED: layer-1 gather (+bias/leaky/dropout) + layer-2 GEMM ----
    k_fused<<<GGRID, 256, 0, stream>>>(row, col16, dis, Hb, b1, W2t, Hb2,
                                       k1a, k1b);

    // ---- layer-2 gather + fused classifier ----
    k_gather2<<<GGRID, 256, 0, stream>>>(row, col16, dis, Hb2, b2, W3, h3s,
                                         k2a, k2b);

    // ---- layer 3 aggregate + log_softmax ----
    k_gather3<<<(N_NODES + G3NODES - 1) / G3NODES, 256, 0, stream>>>(row, col16, dis,
                                                                     h3s, b3, out);
}